// Round 1
// 437.843 us; speedup vs baseline: 1.0717x; 1.0717x over previous
//
#include <hip/hip_runtime.h>
#include <math.h>

#define NNODE 50000
#define NEDGE 800000
#define DIM   128
#define NHEAD 4
#define NTILE ((NNODE + 63) / 64)   // 782
#define NBUCK 196                    // ceil(NNODE/256) coarse buckets (dst>>8)
#define ECHUNK 196                   // ceil(NEDGE/4096) edge chunks
#define CAP   6144                   // per-bucket LDS sort capacity (mean 4082)

typedef __bf16 bf16x8 __attribute__((ext_vector_type(8)));
typedef float  f32x4  __attribute__((ext_vector_type(4)));
typedef float  f32x2  __attribute__((ext_vector_type(2)));

static __device__ __forceinline__ void bfsplit(float x, ushort& hi, ushort& lo) {
    __bf16 h = (__bf16)x;
    float hf = (float)h;
    __bf16 l = (__bf16)(x - hf);
    hi = __builtin_bit_cast(unsigned short, h);
    lo = __builtin_bit_cast(unsigned short, l);
}
static __device__ __forceinline__ ushort f2h(float x) {
    _Float16 h = (_Float16)x;
    return __builtin_bit_cast(unsigned short, h);
}
static __device__ __forceinline__ f32x2 up2v(unsigned u) {
    f32x2 r;
    r.x = (float)__builtin_bit_cast(_Float16, (unsigned short)(u & 0xffff));
    r.y = (float)__builtin_bit_cast(_Float16, (unsigned short)(u >> 16));
    return r;
}
// monotone float<->uint encoding for atomicMax on floats
static __device__ __forceinline__ unsigned encf(float f) {
    unsigned u = __builtin_bit_cast(unsigned, f);
    return (u >> 31) ? ~u : (u | 0x80000000u);
}
static __device__ __forceinline__ float decf(unsigned x) {
    unsigned u = (x >> 31) ? (x & 0x7fffffffu) : ~x;
    return __builtin_bit_cast(float, u);
}

// ---------------------------------------------------------------------------
// CSR build via two-level counting sort (no random 4B global scatters).
// ---------------------------------------------------------------------------
__global__ __launch_bounds__(256) void bhist(const int* __restrict__ eA,
                                             const int* __restrict__ eB,
                                             int* __restrict__ bcnt) {
    int rel = (int)(blockIdx.x >= ECHUNK);
    const int* dstrow = (rel ? eB : eA) + NEDGE;
    int blk = blockIdx.x - rel * ECHUNK;
    __shared__ int hist[256];
    hist[threadIdx.x] = 0;
    __syncthreads();
    int base = blk * 4096;
    #pragma unroll
    for (int k = 0; k < 16; k++) {
        int e = base + k * 256 + threadIdx.x;
        if (e < NEDGE) atomicAdd(&hist[dstrow[e] >> 8], 1);
    }
    __syncthreads();
    int h = hist[threadIdx.x];
    if (h) atomicAdd(&bcnt[rel * 256 + threadIdx.x], h);
}

__global__ __launch_bounds__(256) void bscan(const int* __restrict__ bcnt,
                                             int* __restrict__ bko, int* __restrict__ bcur,
                                             int* __restrict__ ptrA, int* __restrict__ ptrB) {
    int rel = blockIdx.x;
    __shared__ int tmp[256];
    int t = threadIdx.x;
    int v = bcnt[rel * 256 + t];
    tmp[t] = v; __syncthreads();
    for (int off = 1; off < 256; off <<= 1) {
        int a = (t >= off) ? tmp[t - off] : 0; __syncthreads();
        tmp[t] += a; __syncthreads();
    }
    int excl = tmp[t] - v;
    bko[rel * 256 + t] = excl;
    bcur[rel * 256 + t] = excl;
    if (t == 255) (rel ? ptrB : ptrA)[NNODE] = tmp[255];
}

__global__ __launch_bounds__(256) void bscatter(const int* __restrict__ eA,
                                                const int* __restrict__ eB,
                                                int* __restrict__ bcur,
                                                unsigned* __restrict__ bktA,
                                                unsigned* __restrict__ bktB) {
    int rel = (int)(blockIdx.x >= ECHUNK);
    const int* ebase = rel ? eB : eA;
    unsigned* bkt = rel ? bktB : bktA;
    int blk = blockIdx.x - rel * ECHUNK;
    __shared__ int hist[256], bas[256], cur[256];
    hist[threadIdx.x] = 0;
    __syncthreads();
    int base = blk * 4096;
    #pragma unroll
    for (int k = 0; k < 16; k++) {
        int e = base + k * 256 + threadIdx.x;
        if (e < NEDGE) atomicAdd(&hist[ebase[NEDGE + e] >> 8], 1);
    }
    __syncthreads();
    int h = hist[threadIdx.x];
    bas[threadIdx.x] = h ? atomicAdd(&bcur[rel * 256 + threadIdx.x], h) : 0;
    cur[threadIdx.x] = 0;
    __syncthreads();
    #pragma unroll
    for (int k = 0; k < 16; k++) {
        int e = base + k * 256 + threadIdx.x;
        if (e < NEDGE) {
            int s = ebase[e], d = ebase[NEDGE + e];
            int b = d >> 8;
            int loc = atomicAdd(&cur[b], 1);
            bkt[bas[b] + loc] = ((unsigned)(d & 255) << 16) | (unsigned)s;
        }
    }
}

// per-bucket exact sort in LDS -> coalesced srcs (ushort) + ptr for free.
// (dsts array no longer needed: alpha is computed inside agg now)
__global__ __launch_bounds__(256) void bsort(const unsigned* __restrict__ bktA,
                                             const unsigned* __restrict__ bktB,
                                             const int* __restrict__ bko,
                                             int* __restrict__ ptrA, int* __restrict__ ptrB,
                                             ushort* __restrict__ srcA, ushort* __restrict__ srcB) {
    int rel = (int)(blockIdx.x >= NBUCK);
    const unsigned* bkt = rel ? bktB : bktA;
    int* ptr   = rel ? ptrB : ptrA;
    ushort* srcs = rel ? srcB : srcA;
    int b = blockIdx.x - rel * NBUCK;
    int beg = bko[rel * 256 + b], end = bko[rel * 256 + b + 1];
    int cnt_e = end - beg;
    __shared__ int hist[256], excl[256], cur[256];
    __shared__ unsigned sorted[CAP];
    int t = threadIdx.x;
    hist[t] = 0;
    __syncthreads();
    for (int i = t; i < cnt_e; i += 256) atomicAdd(&hist[bkt[beg + i] >> 16], 1);
    __syncthreads();
    int v = hist[t];
    excl[t] = v; __syncthreads();
    for (int off = 1; off < 256; off <<= 1) {
        int a = (t >= off) ? excl[t - off] : 0; __syncthreads();
        excl[t] += a; __syncthreads();
    }
    int ex = excl[t] - v;
    int d = b * 256 + t;
    if (d < NNODE) ptr[d] = beg + ex;
    cur[t] = ex;
    __syncthreads();
    for (int i = t; i < cnt_e; i += 256) {
        unsigned u = bkt[beg + i];
        int dl = u >> 16;
        int p = atomicAdd(&cur[dl], 1);
        if (p < CAP) sorted[p] = u;
        else srcs[beg + p] = (ushort)(u & 0xffffu);  // unreachable overflow path
    }
    __syncthreads();
    int lim = cnt_e < CAP ? cnt_e : CAP;
    for (int i = t; i < lim; i += 256) {
        unsigned u = sorted[i];
        srcs[beg + i] = (ushort)(u & 0xffffu);
    }
}

// ---------------------------------------------------------------------------
// wav[call][k][8]: cols 0..3 = was (Wsrc·a_src), 4..7 = wad (Wdst·a_dst)
// ---------------------------------------------------------------------------
__global__ void prep_wav(const float* __restrict__ Wsrc_fn, const float* __restrict__ a_src_fn,
                         const float* __restrict__ Wdst_fn, const float* __restrict__ a_dst_fn,
                         const float* __restrict__ Wsrc_nf, const float* __restrict__ a_src_nf,
                         const float* __restrict__ Wdst_nf, const float* __restrict__ a_dst_nf,
                         float* __restrict__ wav) {
    int call = blockIdx.x;
    int layer = call >> 1, which = call & 1;
    const float* Ws = which ? Wsrc_nf : Wsrc_fn;
    const float* as = which ? a_src_nf : a_src_fn;
    const float* Wd = which ? Wdst_fn : Wdst_nf;
    const float* ad = which ? a_dst_fn : a_dst_nf;
    Ws += layer * DIM * DIM; Wd += layer * DIM * DIM;
    as += layer * DIM; ad += layer * DIM;
    for (int it = threadIdx.x; it < 512; it += 256) {
        int k = it >> 2, h = it & 3;
        float s = 0.f, dv = 0.f;
        #pragma unroll 8
        for (int c = 0; c < 32; c++) {
            s  += Ws[k * DIM + h * 32 + c] * as[h * 32 + c];
            dv += Wd[k * DIM + h * 32 + c] * ad[h * 32 + c];
        }
        float* o = wav + (size_t)call * DIM * 8 + k * 8;
        o[h] = s; o[h + 4] = dv;
    }
}

// ---------------------------------------------------------------------------
// Transform (split-bf16 MFMA): HS(fp16) = X @ W ; [AS|AD] = X @ wav (MFMA too)
// ---------------------------------------------------------------------------
__global__ __launch_bounds__(256, 3) void transform_kernel(
    const float* __restrict__ XA, const float* __restrict__ WA, const float* __restrict__ wavA,
    ushort* __restrict__ HSA, float* __restrict__ ASA, float* __restrict__ ADA,
    const float* __restrict__ XB, const float* __restrict__ WB, const float* __restrict__ wavB,
    ushort* __restrict__ HSB, float* __restrict__ ASB, float* __restrict__ ADB,
    unsigned* __restrict__ Mg, int nb)
{
    int rel = (int)(blockIdx.x >= (unsigned)nb);
    const float* X  = rel ? XB : XA;
    const float* W  = rel ? WB : WA;
    const float* wav = rel ? wavB : wavA;
    ushort* HS = rel ? HSB : HSA;
    float*  AS = rel ? ASB : ASA;
    float*  AD = rel ? ADB : ADA;

    __shared__ ushort WTh[64][136], WTl[64][136];     // W^T[col][k] hi/lo
    __shared__ ushort wavTh[16][136], wavTl[16][136]; // wav^T[oi][k], oi>=8 zero
    __shared__ unsigned mloc[4];

    int vb = blockIdx.x - rel * nb;
    int half = vb & 1;
    int ch = half * 64;

    for (int i = threadIdx.x; i < 64 * DIM; i += 256) {
        int col = i & 63, k = i >> 6;
        ushort hi, lo; bfsplit(W[k * DIM + ch + col], hi, lo);
        WTh[col][k] = hi; WTl[col][k] = lo;
    }
    for (int i = threadIdx.x; i < 16 * DIM; i += 256) {
        int c = i & 15, k = i >> 4;
        float w = (c < 8) ? wav[k * 8 + c] : 0.f;
        ushort hi, lo; bfsplit(w, hi, lo);
        wavTh[c][k] = hi; wavTl[c][k] = lo;
    }
    if (threadIdx.x < 4) mloc[threadIdx.x] = 0;
    __syncthreads();

    const int wv = threadIdx.x >> 6, lane = threadIdx.x & 63;
    const int lm = lane & 15, lq = lane >> 4;
    const int r0 = wv * 16;

    for (int tile = vb >> 1; tile < NTILE; tile += (nb >> 1)) {
        int row0 = tile * 64;
        int myrow = row0 + r0 + lm;
        int rowc = myrow < NNODE ? myrow : NNODE - 1;   // clamp (dup is harmless)
        const float4* Xr = (const float4*)(X + (size_t)rowc * DIM);

        float4 xv[8];
        #pragma unroll
        for (int kc = 0; kc < 4; kc++) {
            xv[kc * 2]     = Xr[kc * 8 + lq * 2];
            xv[kc * 2 + 1] = Xr[kc * 8 + lq * 2 + 1];
        }

        f32x4 acc[4] = {{0,0,0,0},{0,0,0,0},{0,0,0,0},{0,0,0,0}};
        f32x4 accv = {0,0,0,0};
        #pragma unroll
        for (int kc = 0; kc < 4; kc++) {
            const float* fp = (const float*)&xv[kc * 2];
            bf16x8 ah, al;
            #pragma unroll
            for (int j = 0; j < 8; j++) {
                float x = fp[j];
                __bf16 h = (__bf16)x;
                ah[j] = h;
                al[j] = (__bf16)(x - (float)h);
            }
            int k0 = kc * 32 + lq * 8;
            #pragma unroll
            for (int ct = 0; ct < 4; ct++) {
                bf16x8 bh = *(const bf16x8*)&WTh[ct * 16 + lm][k0];
                bf16x8 bl = *(const bf16x8*)&WTl[ct * 16 + lm][k0];
                acc[ct] = __builtin_amdgcn_mfma_f32_16x16x32_bf16(al, bh, acc[ct], 0, 0, 0);
                acc[ct] = __builtin_amdgcn_mfma_f32_16x16x32_bf16(ah, bl, acc[ct], 0, 0, 0);
                acc[ct] = __builtin_amdgcn_mfma_f32_16x16x32_bf16(ah, bh, acc[ct], 0, 0, 0);
            }
            if (half == 0) {
                bf16x8 vh = *(const bf16x8*)&wavTh[lm][k0];
                bf16x8 vl = *(const bf16x8*)&wavTl[lm][k0];
                accv = __builtin_amdgcn_mfma_f32_16x16x32_bf16(al, vh, accv, 0, 0, 0);
                accv = __builtin_amdgcn_mfma_f32_16x16x32_bf16(ah, vl, accv, 0, 0, 0);
                accv = __builtin_amdgcn_mfma_f32_16x16x32_bf16(ah, vh, accv, 0, 0, 0);
            }
        }

        #pragma unroll
        for (int ct = 0; ct < 4; ct++) {
            #pragma unroll
            for (int r = 0; r < 4; r++) {
                int row = row0 + r0 + lq * 4 + r;
                if (row < NNODE) HS[(size_t)row * DIM + ch + ct * 16 + lm] = f2h(acc[ct][r]);
            }
        }
        if (half == 0 && lm < 8) {
            float mx4 = -INFINITY;
            #pragma unroll
            for (int r = 0; r < 4; r++) {
                int row = row0 + r0 + lq * 4 + r;
                if (row < NNODE) {
                    if (lm < 4) AS[row * 4 + lm] = accv[r];
                    else        AD[row * 4 + (lm - 4)] = accv[r];
                }
                mx4 = fmaxf(mx4, accv[r]);
            }
            if (lm < 4) atomicMax(&mloc[lm], encf(mx4));
        }
    }
    __syncthreads();
    if (half == 0 && threadIdx.x < 4)
        atomicMax(&Mg[rel * 4 + threadIdx.x], mloc[threadIdx.x]);
}

// ---------------------------------------------------------------------------
// Fused aggregation: one wave per dst node. Per edge, alpha is computed
// inline: p = exp(lrelu(AS[s,h]+AD[d,h]) - mm), mm = lrelu(maxAS_h + AD[d,h])
// (wave-uniform, >= segment max; softmax is shift-invariant).
// src index is made wave-uniform via readfirstlane -> SGPR-based (saddr)
// gathers, 8 independent gather chains in flight per wave.
// Fuses softmax-normalize + bias + ELU.
// ---------------------------------------------------------------------------
__global__ __launch_bounds__(256) void agg_kernel(
    const ushort* __restrict__ HSA, const float* __restrict__ ASA, const float* __restrict__ ADA,
    const int* __restrict__ ptrA, const ushort* __restrict__ srcA,
    const float* __restrict__ biasA, float* __restrict__ outA,
    const ushort* __restrict__ HSB, const float* __restrict__ ASB, const float* __restrict__ ADB,
    const int* __restrict__ ptrB, const ushort* __restrict__ srcB,
    const float* __restrict__ biasB, float* __restrict__ outB,
    const unsigned* __restrict__ Mg, int nb)
{
    int rel = (int)(blockIdx.x >= (unsigned)nb);
    const unsigned* HSu = (const unsigned*)(rel ? HSB : HSA);
    const float* AS = rel ? ASB : ASA;
    const float* AD = rel ? ADB : ADA;
    const ushort* srcs = rel ? srcB : srcA;
    const int* ptr = rel ? ptrB : ptrA;
    const float* bias = rel ? biasB : biasA;
    float* out = rel ? outB : outA;

    int bid = blockIdx.x - rel * nb;
    int wave = threadIdx.x >> 6, lane = threadIdx.x & 63;
    int d = bid * 4 + wave;
    if (d >= NNODE) return;
    int hh = lane >> 4;

    float ad_h = AD[d * 4 + hh];
    float mm = decf(Mg[rel * 4 + hh]) + ad_h;
    mm = mm > 0.f ? mm : 0.2f * mm;

    int e0 = ptr[d], e1 = ptr[d + 1];

    f32x2 acc0 = {0.f, 0.f}, acc1 = acc0, acc2 = acc0, acc3 = acc0;
    float l0 = 0.f, l1 = 0.f, l2 = 0.f, l3 = 0.f;
    int e = e0;

    for (; e + 8 <= e1; e += 8) {
        ushort sv[8];
        #pragma unroll
        for (int k = 0; k < 8; k++) sv[k] = srcs[e + k];
        unsigned u[8]; float av[8];
        #pragma unroll
        for (int k = 0; k < 8; k++) {
            int s = __builtin_amdgcn_readfirstlane((int)sv[k]);
            u[k] = HSu[(s << 6) + lane];
            av[k] = AS[(s << 2) + hh];
        }
        #pragma unroll
        for (int k = 0; k < 8; k++) {
            float v = av[k] + ad_h;
            v = v > 0.f ? v : 0.2f * v;
            float p = __expf(v - mm);
            f32x2 h = up2v(u[k]);
            if ((k & 3) == 0)      { acc0 += h * p; l0 += p; }
            else if ((k & 3) == 1) { acc1 += h * p; l1 += p; }
            else if ((k & 3) == 2) { acc2 += h * p; l2 += p; }
            else                   { acc3 += h * p; l3 += p; }
        }
    }
    for (; e + 4 <= e1; e += 4) {
        ushort sv[4];
        #pragma unroll
        for (int k = 0; k < 4; k++) sv[k] = srcs[e + k];
        unsigned u[4]; float av[4];
        #pragma unroll
        for (int k = 0; k < 4; k++) {
            int s = __builtin_amdgcn_readfirstlane((int)sv[k]);
            u[k] = HSu[(s << 6) + lane];
            av[k] = AS[(s << 2) + hh];
        }
        #pragma unroll
        for (int k = 0; k < 4; k++) {
            float v = av[k] + ad_h;
            v = v > 0.f ? v : 0.2f * v;
            float p = __expf(v - mm);
            f32x2 h = up2v(u[k]);
            if (k == 0)      { acc0 += h * p; l0 += p; }
            else if (k == 1) { acc1 += h * p; l1 += p; }
            else if (k == 2) { acc2 += h * p; l2 += p; }
            else             { acc3 += h * p; l3 += p; }
        }
    }
    for (; e < e1; e++) {
        int s = __builtin_amdgcn_readfirstlane((int)srcs[e]);
        unsigned u = HSu[(s << 6) + lane];
        float v = AS[(s << 2) + hh] + ad_h;
        v = v > 0.f ? v : 0.2f * v;
        float p = __expf(v - mm);
        f32x2 h = up2v(u);
        acc0 += h * p; l0 += p;
    }

    f32x2 acc = (acc0 + acc1) + (acc2 + acc3);
    float l = (l0 + l1) + (l2 + l3);

    int j0 = lane * 2;
    float inv = 1.f / (l + 1e-16f);
    float o0 = acc.x * inv + bias[j0];
    float o1 = acc.y * inv + bias[j0 + 1];
    o0 = o0 > 0.f ? o0 : __expf(o0) - 1.f;   // ELU
    o1 = o1 > 0.f ? o1 : __expf(o1) - 1.f;
    *(float2*)&out[(size_t)d * DIM + j0] = make_float2(o0, o1);
}

// ---------------------------------------------------------------------------
extern "C" void kernel_launch(void* const* d_in, const int* in_sizes, int n_in,
                              void* d_out, int out_size, void* d_ws, size_t ws_size,
                              hipStream_t stream) {
    const float* x_food      = (const float*)d_in[0];
    const float* x_nut       = (const float*)d_in[1];
    const float* Wsrc_fn     = (const float*)d_in[2];
    const float* Wdst_fn     = (const float*)d_in[3];
    const float* att_src_fn  = (const float*)d_in[4];
    const float* att_dst_fn  = (const float*)d_in[5];
    const float* bias_fn     = (const float*)d_in[6];
    const float* Wsrc_nf     = (const float*)d_in[7];
    const float* Wdst_nf     = (const float*)d_in[8];
    const float* att_src_nf  = (const float*)d_in[9];
    const float* att_dst_nf  = (const float*)d_in[10];
    const float* bias_nf     = (const float*)d_in[11];
    const int*   ei_fn       = (const int*)d_in[12];
    const int*   ei_nf       = (const int*)d_in[13];
    float* out = (float*)d_out;

    char* ws = (char*)d_ws;
    size_t off = 0;
    auto alloc_f = [&](size_t n) { float* p = (float*)(ws + off); off += n * 4; return p; };
    auto alloc_i = [&](size_t n) { int* p = (int*)(ws + off); off += n * 4; return p; };
    auto alloc_u = [&](size_t n) { ushort* p = (ushort*)(ws + off); off += n * 2; return p; };

    float* B_food = alloc_f((size_t)NNODE * DIM);
    float* B_nut  = alloc_f((size_t)NNODE * DIM);
    ushort* HS_fn = alloc_u((size_t)NNODE * DIM);
    ushort* HS_nf = alloc_u((size_t)NNODE * DIM);
    float* AS_fn  = alloc_f(NNODE * NHEAD);
    float* AS_nf  = alloc_f(NNODE * NHEAD);
    float* AD_fn  = alloc_f(NNODE * NHEAD);
    float* AD_nf  = alloc_f(NNODE * NHEAD);
    float* wav    = alloc_f(4 * DIM * 8);
    int* ptr_fn   = alloc_i(50004);
    int* ptr_nf   = alloc_i(50004);
    ushort* srcs_fn = alloc_u(NEDGE);
    ushort* srcs_nf = alloc_u(NEDGE);
    int* bcnt     = alloc_i(512);
    unsigned* Mbuf = (unsigned*)alloc_i(16);   // [layer][rel][head]
    int* bko      = alloc_i(512);
    int* bcur     = alloc_i(512);
    // bkt buffers alias B_food/B_nut (dead until after CSR build)
    unsigned* bkt_fn = (unsigned*)B_food;
    unsigned* bkt_nf = (unsigned*)B_nut;

    // ---- CSR build: two-level counting sort (+ zero Mbuf, contiguous) ----
    hipMemsetAsync(bcnt, 0, (512 + 16) * 4, stream);
    bhist<<<2 * ECHUNK, 256, 0, stream>>>(ei_fn, ei_nf, bcnt);
    bscan<<<2, 256, 0, stream>>>(bcnt, bko, bcur, ptr_fn, ptr_nf);
    bscatter<<<2 * ECHUNK, 256, 0, stream>>>(ei_fn, ei_nf, bcur, bkt_fn, bkt_nf);
    bsort<<<2 * NBUCK, 256, 0, stream>>>(bkt_fn, bkt_nf, bko, ptr_fn, ptr_nf,
                                         srcs_fn, srcs_nf);

    prep_wav<<<4, 256, 0, stream>>>(Wsrc_fn, att_src_fn, Wdst_fn, att_dst_fn,
                                    Wsrc_nf, att_src_nf, Wdst_nf, att_dst_nf, wav);

    const int WL = DIM * DIM;
    const int TNB = 768;
    const int ANB = (NNODE + 3) / 4;
    float* wav0 = wav;
    float* wav1 = wav + DIM * 8;
    float* wav2 = wav + 2 * DIM * 8;
    float* wav3 = wav + 3 * DIM * 8;

    // ---- Layer 0 ----
    transform_kernel<<<2 * TNB, 256, 0, stream>>>(
        x_food, Wsrc_fn, wav0, HS_fn, AS_fn, AD_nf,
        x_nut,  Wsrc_nf, wav1, HS_nf, AS_nf, AD_fn, Mbuf, TNB);
    agg_kernel<<<2 * ANB, 256, 0, stream>>>(
        HS_fn, AS_fn, AD_fn, ptr_fn, srcs_fn, bias_fn, B_nut,
        HS_nf, AS_nf, AD_nf, ptr_nf, srcs_nf, bias_nf, B_food, Mbuf, ANB);

    // ---- Layer 1 -> d_out ----
    transform_kernel<<<2 * TNB, 256, 0, stream>>>(
        B_food, Wsrc_fn + WL, wav2, HS_fn, AS_fn, AD_nf,
        B_nut,  Wsrc_nf + WL, wav3, HS_nf, AS_nf, AD_fn, Mbuf + 8, TNB);
    agg_kernel<<<2 * ANB, 256, 0, stream>>>(
        HS_fn, AS_fn, AD_fn, ptr_fn, srcs_fn, bias_fn + DIM, out + (size_t)NNODE * DIM,
        HS_nf, AS_nf, AD_nf, ptr_nf, srcs_nf, bias_nf + DIM, out, Mbuf + 8, ANB);
}

// Round 2
// 423.515 us; speedup vs baseline: 1.1080x; 1.0338x over previous
//
#include <hip/hip_runtime.h>
#include <math.h>

#define NNODE 50000
#define NEDGE 800000
#define DIM   128
#define NHEAD 4
#define NTILE ((NNODE + 63) / 64)   // 782
#define NBUCK 196                    // ceil(NNODE/256) coarse buckets (dst>>8)
#define ECHUNK 196                   // ceil(NEDGE/4096) edge chunks
#define CAP   6144                   // per-bucket LDS sort capacity (mean 4082)
#define LOG2E 1.44269504088896340736f

typedef __bf16 bf16x8 __attribute__((ext_vector_type(8)));
typedef float  f32x4  __attribute__((ext_vector_type(4)));
typedef float  f32x2  __attribute__((ext_vector_type(2)));

static __device__ __forceinline__ void bfsplit(float x, ushort& hi, ushort& lo) {
    __bf16 h = (__bf16)x;
    float hf = (float)h;
    __bf16 l = (__bf16)(x - hf);
    hi = __builtin_bit_cast(unsigned short, h);
    lo = __builtin_bit_cast(unsigned short, l);
}
static __device__ __forceinline__ ushort f2h(float x) {
    _Float16 h = (_Float16)x;
    return __builtin_bit_cast(unsigned short, h);
}
static __device__ __forceinline__ f32x2 up2v(unsigned u) {
    f32x2 r;
    r.x = (float)__builtin_bit_cast(_Float16, (unsigned short)(u & 0xffff));
    r.y = (float)__builtin_bit_cast(_Float16, (unsigned short)(u >> 16));
    return r;
}
// monotone float<->uint encoding for atomicMax on floats
static __device__ __forceinline__ unsigned encf(float f) {
    unsigned u = __builtin_bit_cast(unsigned, f);
    return (u >> 31) ? ~u : (u | 0x80000000u);
}
static __device__ __forceinline__ float decf(unsigned x) {
    unsigned u = (x >> 31) ? (x & 0x7fffffffu) : ~x;
    return __builtin_bit_cast(float, u);
}

// ---------------------------------------------------------------------------
// CSR build via two-level counting sort (no random 4B global scatters).
// ---------------------------------------------------------------------------
__global__ __launch_bounds__(256) void bhist(const int* __restrict__ eA,
                                             const int* __restrict__ eB,
                                             int* __restrict__ bcnt) {
    int rel = (int)(blockIdx.x >= ECHUNK);
    const int* dstrow = (rel ? eB : eA) + NEDGE;
    int blk = blockIdx.x - rel * ECHUNK;
    __shared__ int hist[256];
    hist[threadIdx.x] = 0;
    __syncthreads();
    int base = blk * 4096;
    #pragma unroll
    for (int k = 0; k < 16; k++) {
        int e = base + k * 256 + threadIdx.x;
        if (e < NEDGE) atomicAdd(&hist[dstrow[e] >> 8], 1);
    }
    __syncthreads();
    int h = hist[threadIdx.x];
    if (h) atomicAdd(&bcnt[rel * 256 + threadIdx.x], h);
}

__global__ __launch_bounds__(256) void bscan(const int* __restrict__ bcnt,
                                             int* __restrict__ bko, int* __restrict__ bcur,
                                             int* __restrict__ ptrA, int* __restrict__ ptrB) {
    int rel = blockIdx.x;
    __shared__ int tmp[256];
    int t = threadIdx.x;
    int v = bcnt[rel * 256 + t];
    tmp[t] = v; __syncthreads();
    for (int off = 1; off < 256; off <<= 1) {
        int a = (t >= off) ? tmp[t - off] : 0; __syncthreads();
        tmp[t] += a; __syncthreads();
    }
    int excl = tmp[t] - v;
    bko[rel * 256 + t] = excl;
    bcur[rel * 256 + t] = excl;
    if (t == 255) (rel ? ptrB : ptrA)[NNODE] = tmp[255];
}

__global__ __launch_bounds__(256) void bscatter(const int* __restrict__ eA,
                                                const int* __restrict__ eB,
                                                int* __restrict__ bcur,
                                                unsigned* __restrict__ bktA,
                                                unsigned* __restrict__ bktB) {
    int rel = (int)(blockIdx.x >= ECHUNK);
    const int* ebase = rel ? eB : eA;
    unsigned* bkt = rel ? bktB : bktA;
    int blk = blockIdx.x - rel * ECHUNK;
    __shared__ int hist[256], bas[256], cur[256];
    hist[threadIdx.x] = 0;
    __syncthreads();
    int base = blk * 4096;
    #pragma unroll
    for (int k = 0; k < 16; k++) {
        int e = base + k * 256 + threadIdx.x;
        if (e < NEDGE) atomicAdd(&hist[ebase[NEDGE + e] >> 8], 1);
    }
    __syncthreads();
    int h = hist[threadIdx.x];
    bas[threadIdx.x] = h ? atomicAdd(&bcur[rel * 256 + threadIdx.x], h) : 0;
    cur[threadIdx.x] = 0;
    __syncthreads();
    #pragma unroll
    for (int k = 0; k < 16; k++) {
        int e = base + k * 256 + threadIdx.x;
        if (e < NEDGE) {
            int s = ebase[e], d = ebase[NEDGE + e];
            int b = d >> 8;
            int loc = atomicAdd(&cur[b], 1);
            bkt[bas[b] + loc] = ((unsigned)(d & 255) << 16) | (unsigned)s;
        }
    }
}

// per-bucket exact sort in LDS -> coalesced srcs (ushort) + ptr for free.
__global__ __launch_bounds__(256) void bsort(const unsigned* __restrict__ bktA,
                                             const unsigned* __restrict__ bktB,
                                             const int* __restrict__ bko,
                                             int* __restrict__ ptrA, int* __restrict__ ptrB,
                                             ushort* __restrict__ srcA, ushort* __restrict__ srcB) {
    int rel = (int)(blockIdx.x >= NBUCK);
    const unsigned* bkt = rel ? bktB : bktA;
    int* ptr   = rel ? ptrB : ptrA;
    ushort* srcs = rel ? srcB : srcA;
    int b = blockIdx.x - rel * NBUCK;
    int beg = bko[rel * 256 + b], end = bko[rel * 256 + b + 1];
    int cnt_e = end - beg;
    __shared__ int hist[256], excl[256], cur[256];
    __shared__ unsigned sorted[CAP];
    int t = threadIdx.x;
    hist[t] = 0;
    __syncthreads();
    for (int i = t; i < cnt_e; i += 256) atomicAdd(&hist[bkt[beg + i] >> 16], 1);
    __syncthreads();
    int v = hist[t];
    excl[t] = v; __syncthreads();
    for (int off = 1; off < 256; off <<= 1) {
        int a = (t >= off) ? excl[t - off] : 0; __syncthreads();
        excl[t] += a; __syncthreads();
    }
    int ex = excl[t] - v;
    int d = b * 256 + t;
    if (d < NNODE) ptr[d] = beg + ex;
    cur[t] = ex;
    __syncthreads();
    for (int i = t; i < cnt_e; i += 256) {
        unsigned u = bkt[beg + i];
        int dl = u >> 16;
        int p = atomicAdd(&cur[dl], 1);
        if (p < CAP) sorted[p] = u;
        else srcs[beg + p] = (ushort)(u & 0xffffu);  // unreachable overflow path
    }
    __syncthreads();
    int lim = cnt_e < CAP ? cnt_e : CAP;
    for (int i = t; i < lim; i += 256) {
        unsigned u = sorted[i];
        srcs[beg + i] = (ushort)(u & 0xffffu);
    }
}

// ---------------------------------------------------------------------------
// wav[call][k][8]: cols 0..3 = was (Wsrc·a_src), 4..7 = wad (Wdst·a_dst)
// ---------------------------------------------------------------------------
__global__ void prep_wav(const float* __restrict__ Wsrc_fn, const float* __restrict__ a_src_fn,
                         const float* __restrict__ Wdst_fn, const float* __restrict__ a_dst_fn,
                         const float* __restrict__ Wsrc_nf, const float* __restrict__ a_src_nf,
                         const float* __restrict__ Wdst_nf, const float* __restrict__ a_dst_nf,
                         float* __restrict__ wav) {
    int call = blockIdx.x;
    int layer = call >> 1, which = call & 1;
    const float* Ws = which ? Wsrc_nf : Wsrc_fn;
    const float* as = which ? a_src_nf : a_src_fn;
    const float* Wd = which ? Wdst_fn : Wdst_nf;
    const float* ad = which ? a_dst_fn : a_dst_nf;
    Ws += layer * DIM * DIM; Wd += layer * DIM * DIM;
    as += layer * DIM; ad += layer * DIM;
    for (int it = threadIdx.x; it < 512; it += 256) {
        int k = it >> 2, h = it & 3;
        float s = 0.f, dv = 0.f;
        #pragma unroll 8
        for (int c = 0; c < 32; c++) {
            s  += Ws[k * DIM + h * 32 + c] * as[h * 32 + c];
            dv += Wd[k * DIM + h * 32 + c] * ad[h * 32 + c];
        }
        float* o = wav + (size_t)call * DIM * 8 + k * 8;
        o[h] = s; o[h + 4] = dv;
    }
}

// ---------------------------------------------------------------------------
// Transform (split-bf16 MFMA): HS(fp16) = X @ W ; [AS|AD] = X @ wav (MFMA too)
// AS/AD/max are pre-scaled by log2(e) so agg can use raw v_exp_f32 (exp2).
// lrelu is positive-scale-invariant so the softmax is unchanged.
// ---------------------------------------------------------------------------
__global__ __launch_bounds__(256, 3) void transform_kernel(
    const float* __restrict__ XA, const float* __restrict__ WA, const float* __restrict__ wavA,
    ushort* __restrict__ HSA, float* __restrict__ ASA, float* __restrict__ ADA,
    const float* __restrict__ XB, const float* __restrict__ WB, const float* __restrict__ wavB,
    ushort* __restrict__ HSB, float* __restrict__ ASB, float* __restrict__ ADB,
    unsigned* __restrict__ Mg, int nb)
{
    int rel = (int)(blockIdx.x >= (unsigned)nb);
    const float* X  = rel ? XB : XA;
    const float* W  = rel ? WB : WA;
    const float* wav = rel ? wavB : wavA;
    ushort* HS = rel ? HSB : HSA;
    float*  AS = rel ? ASB : ASA;
    float*  AD = rel ? ADB : ADA;

    __shared__ ushort WTh[64][136], WTl[64][136];     // W^T[col][k] hi/lo
    __shared__ ushort wavTh[16][136], wavTl[16][136]; // wav^T[oi][k], oi>=8 zero
    __shared__ unsigned mloc[4];

    int vb = blockIdx.x - rel * nb;
    int half = vb & 1;
    int ch = half * 64;

    for (int i = threadIdx.x; i < 64 * DIM; i += 256) {
        int col = i & 63, k = i >> 6;
        ushort hi, lo; bfsplit(W[k * DIM + ch + col], hi, lo);
        WTh[col][k] = hi; WTl[col][k] = lo;
    }
    for (int i = threadIdx.x; i < 16 * DIM; i += 256) {
        int c = i & 15, k = i >> 4;
        float w = (c < 8) ? wav[k * 8 + c] : 0.f;
        ushort hi, lo; bfsplit(w, hi, lo);
        wavTh[c][k] = hi; wavTl[c][k] = lo;
    }
    if (threadIdx.x < 4) mloc[threadIdx.x] = 0;
    __syncthreads();

    const int wv = threadIdx.x >> 6, lane = threadIdx.x & 63;
    const int lm = lane & 15, lq = lane >> 4;
    const int r0 = wv * 16;

    for (int tile = vb >> 1; tile < NTILE; tile += (nb >> 1)) {
        int row0 = tile * 64;
        int myrow = row0 + r0 + lm;
        int rowc = myrow < NNODE ? myrow : NNODE - 1;   // clamp (dup is harmless)
        const float4* Xr = (const float4*)(X + (size_t)rowc * DIM);

        float4 xv[8];
        #pragma unroll
        for (int kc = 0; kc < 4; kc++) {
            xv[kc * 2]     = Xr[kc * 8 + lq * 2];
            xv[kc * 2 + 1] = Xr[kc * 8 + lq * 2 + 1];
        }

        f32x4 acc[4] = {{0,0,0,0},{0,0,0,0},{0,0,0,0},{0,0,0,0}};
        f32x4 accv = {0,0,0,0};
        #pragma unroll
        for (int kc = 0; kc < 4; kc++) {
            const float* fp = (const float*)&xv[kc * 2];
            bf16x8 ah, al;
            #pragma unroll
            for (int j = 0; j < 8; j++) {
                float x = fp[j];
                __bf16 h = (__bf16)x;
                ah[j] = h;
                al[j] = (__bf16)(x - (float)h);
            }
            int k0 = kc * 32 + lq * 8;
            #pragma unroll
            for (int ct = 0; ct < 4; ct++) {
                bf16x8 bh = *(const bf16x8*)&WTh[ct * 16 + lm][k0];
                bf16x8 bl = *(const bf16x8*)&WTl[ct * 16 + lm][k0];
                acc[ct] = __builtin_amdgcn_mfma_f32_16x16x32_bf16(al, bh, acc[ct], 0, 0, 0);
                acc[ct] = __builtin_amdgcn_mfma_f32_16x16x32_bf16(ah, bl, acc[ct], 0, 0, 0);
                acc[ct] = __builtin_amdgcn_mfma_f32_16x16x32_bf16(ah, bh, acc[ct], 0, 0, 0);
            }
            if (half == 0) {
                bf16x8 vh = *(const bf16x8*)&wavTh[lm][k0];
                bf16x8 vl = *(const bf16x8*)&wavTl[lm][k0];
                accv = __builtin_amdgcn_mfma_f32_16x16x32_bf16(al, vh, accv, 0, 0, 0);
                accv = __builtin_amdgcn_mfma_f32_16x16x32_bf16(ah, vl, accv, 0, 0, 0);
                accv = __builtin_amdgcn_mfma_f32_16x16x32_bf16(ah, vh, accv, 0, 0, 0);
            }
        }

        #pragma unroll
        for (int ct = 0; ct < 4; ct++) {
            #pragma unroll
            for (int r = 0; r < 4; r++) {
                int row = row0 + r0 + lq * 4 + r;
                if (row < NNODE) HS[(size_t)row * DIM + ch + ct * 16 + lm] = f2h(acc[ct][r]);
            }
        }
        if (half == 0 && lm < 8) {
            accv *= LOG2E;   // pre-scale so agg uses exp2 directly
            float mx4 = -INFINITY;
            #pragma unroll
            for (int r = 0; r < 4; r++) {
                int row = row0 + r0 + lq * 4 + r;
                if (row < NNODE) {
                    if (lm < 4) AS[row * 4 + lm] = accv[r];
                    else        AD[row * 4 + (lm - 4)] = accv[r];
                }
                mx4 = fmaxf(mx4, accv[r]);
            }
            if (lm < 4) atomicMax(&mloc[lm], encf(mx4));
        }
    }
    __syncthreads();
    if (half == 0 && threadIdx.x < 4)
        atomicMax(&Mg[rel * 4 + threadIdx.x], mloc[threadIdx.x]);
}

// ---------------------------------------------------------------------------
// Fused aggregation, quarter-wave edge slots: one wave per dst node; each
// group of 16 lanes owns one edge (4 edges in flight per wave-instruction),
// each lane owns 8 channels (one uint4 = 8 f16 of the HS row). Alpha math
// runs once per edge-slot instead of replicated 16x. Cross-quarter butterfly
// at the end combines the 4 edge streams. Fuses softmax-normalize+bias+ELU.
// ---------------------------------------------------------------------------
__global__ __launch_bounds__(256) void agg_kernel(
    const ushort* __restrict__ HSA, const float* __restrict__ ASA, const float* __restrict__ ADA,
    const int* __restrict__ ptrA, const ushort* __restrict__ srcA,
    const float* __restrict__ biasA, float* __restrict__ outA,
    const ushort* __restrict__ HSB, const float* __restrict__ ASB, const float* __restrict__ ADB,
    const int* __restrict__ ptrB, const ushort* __restrict__ srcB,
    const float* __restrict__ biasB, float* __restrict__ outB,
    const unsigned* __restrict__ Mg, int nb)
{
    int rel = (int)(blockIdx.x >= (unsigned)nb);
    const uint4* HS4 = (const uint4*)(rel ? HSB : HSA);   // row = 16 uint4
    const float* AS = rel ? ASB : ASA;
    const float* AD = rel ? ADB : ADA;
    const ushort* srcs = rel ? srcB : srcA;
    const int* ptr = rel ? ptrB : ptrA;
    const float* bias = rel ? biasB : biasA;
    float* out = rel ? outB : outA;

    int bid = blockIdx.x - rel * nb;
    int wave = threadIdx.x >> 6, lane = threadIdx.x & 63;
    int d = bid * 4 + wave;
    if (d >= NNODE) return;

    int q  = lane >> 4;        // edge slot 0..3
    int li = lane & 15;        // channel block: channels li*8 .. li*8+7
    int hh = li >> 2;          // head of this channel block

    float ad_h = AD[d * 4 + hh];
    float mm = decf(Mg[rel * 4 + hh]) + ad_h;
    mm = mm > 0.f ? mm : 0.2f * mm;

    int e0 = ptr[d], e1 = ptr[d + 1];

    float acc[8] = {0.f,0.f,0.f,0.f,0.f,0.f,0.f,0.f};
    float l = 0.f;

    int e = e0;
    for (; e + 8 <= e1; e += 8) {           // 2 slots/iter, both fully active
        int iA = e + q, iB = e + 4 + q;
        int sA = srcs[iA], sB = srcs[iB];
        uint4 hA = HS4[sA * 16 + li];
        uint4 hB = HS4[sB * 16 + li];
        float aA = AS[sA * 4 + hh];
        float aB = AS[sB * 4 + hh];
        float vA = aA + ad_h; vA = fmaxf(vA, 0.2f * vA);
        float vB = aB + ad_h; vB = fmaxf(vB, 0.2f * vB);
        float pA = __builtin_amdgcn_exp2f(vA - mm);
        float pB = __builtin_amdgcn_exp2f(vB - mm);
        l += pA + pB;
        #pragma unroll
        for (int j = 0; j < 4; j++) {
            f32x2 h2A = up2v(((const unsigned*)&hA)[j]);
            f32x2 h2B = up2v(((const unsigned*)&hB)[j]);
            acc[2*j]   += h2A.x * pA + h2B.x * pB;
            acc[2*j+1] += h2A.y * pA + h2B.y * pB;
        }
    }
    for (; e < e1; e += 4) {                // predicated tail (<= 2 iters)
        int ee = e + q;
        bool act = ee < e1;
        int eidx = act ? ee : e1 - 1;
        int s = srcs[eidx];
        uint4 hv = HS4[s * 16 + li];
        float av = AS[s * 4 + hh];
        float v = av + ad_h; v = fmaxf(v, 0.2f * v);
        float p = __builtin_amdgcn_exp2f(v - mm);
        p = act ? p : 0.f;
        l += p;
        #pragma unroll
        for (int j = 0; j < 4; j++) {
            f32x2 h2 = up2v(((const unsigned*)&hv)[j]);
            acc[2*j]   += h2.x * p;
            acc[2*j+1] += h2.y * p;
        }
    }

    // combine the 4 edge-slot streams (lanes with equal li, differing q)
    #pragma unroll
    for (int j = 0; j < 8; j++) {
        acc[j] += __shfl_xor(acc[j], 16, 64);
        acc[j] += __shfl_xor(acc[j], 32, 64);
    }
    l += __shfl_xor(l, 16, 64);
    l += __shfl_xor(l, 32, 64);

    if (q == 0) {
        float inv = 1.f / (l + 1e-16f);
        const float4* b4 = (const float4*)bias + li * 2;
        float4 b0 = b4[0], b1 = b4[1];
        float o[8];
        o[0] = acc[0] * inv + b0.x; o[1] = acc[1] * inv + b0.y;
        o[2] = acc[2] * inv + b0.z; o[3] = acc[3] * inv + b0.w;
        o[4] = acc[4] * inv + b1.x; o[5] = acc[5] * inv + b1.y;
        o[6] = acc[6] * inv + b1.z; o[7] = acc[7] * inv + b1.w;
        #pragma unroll
        for (int j = 0; j < 8; j++)
            o[j] = o[j] > 0.f ? o[j] : __expf(o[j]) - 1.f;   // ELU
        float4* o4 = (float4*)(out + (size_t)d * DIM) + li * 2;
        o4[0] = make_float4(o[0], o[1], o[2], o[3]);
        o4[1] = make_float4(o[4], o[5], o[6], o[7]);
    }
}

// ---------------------------------------------------------------------------
extern "C" void kernel_launch(void* const* d_in, const int* in_sizes, int n_in,
                              void* d_out, int out_size, void* d_ws, size_t ws_size,
                              hipStream_t stream) {
    const float* x_food      = (const float*)d_in[0];
    const float* x_nut       = (const float*)d_in[1];
    const float* Wsrc_fn     = (const float*)d_in[2];
    const float* Wdst_fn     = (const float*)d_in[3];
    const float* att_src_fn  = (const float*)d_in[4];
    const float* att_dst_fn  = (const float*)d_in[5];
    const float* bias_fn     = (const float*)d_in[6];
    const float* Wsrc_nf     = (const float*)d_in[7];
    const float* Wdst_nf     = (const float*)d_in[8];
    const float* att_src_nf  = (const float*)d_in[9];
    const float* att_dst_nf  = (const float*)d_in[10];
    const float* bias_nf     = (const float*)d_in[11];
    const int*   ei_fn       = (const int*)d_in[12];
    const int*   ei_nf       = (const int*)d_in[13];
    float* out = (float*)d_out;

    char* ws = (char*)d_ws;
    size_t off = 0;
    auto alloc_f = [&](size_t n) { float* p = (float*)(ws + off); off += n * 4; return p; };
    auto alloc_i = [&](size_t n) { int* p = (int*)(ws + off); off += n * 4; return p; };
    auto alloc_u = [&](size_t n) { ushort* p = (ushort*)(ws + off); off += n * 2; return p; };

    float* B_food = alloc_f((size_t)NNODE * DIM);
    float* B_nut  = alloc_f((size_t)NNODE * DIM);
    ushort* HS_fn = alloc_u((size_t)NNODE * DIM);
    ushort* HS_nf = alloc_u((size_t)NNODE * DIM);
    float* AS_fn  = alloc_f(NNODE * NHEAD);
    float* AS_nf  = alloc_f(NNODE * NHEAD);
    float* AD_fn  = alloc_f(NNODE * NHEAD);
    float* AD_nf  = alloc_f(NNODE * NHEAD);
    float* wav    = alloc_f(4 * DIM * 8);
    int* ptr_fn   = alloc_i(50004);
    int* ptr_nf   = alloc_i(50004);
    ushort* srcs_fn = alloc_u(NEDGE);
    ushort* srcs_nf = alloc_u(NEDGE);
    int* bcnt     = alloc_i(512);
    unsigned* Mbuf = (unsigned*)alloc_i(16);   // [layer][rel][head]
    int* bko      = alloc_i(512);
    int* bcur     = alloc_i(512);
    // bkt buffers alias B_food/B_nut (dead until after CSR build)
    unsigned* bkt_fn = (unsigned*)B_food;
    unsigned* bkt_nf = (unsigned*)B_nut;

    // ---- CSR build: two-level counting sort (+ zero Mbuf, contiguous) ----
    hipMemsetAsync(bcnt, 0, (512 + 16) * 4, stream);
    bhist<<<2 * ECHUNK, 256, 0, stream>>>(ei_fn, ei_nf, bcnt);
    bscan<<<2, 256, 0, stream>>>(bcnt, bko, bcur, ptr_fn, ptr_nf);
    bscatter<<<2 * ECHUNK, 256, 0, stream>>>(ei_fn, ei_nf, bcur, bkt_fn, bkt_nf);
    bsort<<<2 * NBUCK, 256, 0, stream>>>(bkt_fn, bkt_nf, bko, ptr_fn, ptr_nf,
                                         srcs_fn, srcs_nf);

    prep_wav<<<4, 256, 0, stream>>>(Wsrc_fn, att_src_fn, Wdst_fn, att_dst_fn,
                                    Wsrc_nf, att_src_nf, Wdst_nf, att_dst_nf, wav);

    const int WL = DIM * DIM;
    const int TNB = 768;
    const int ANB = (NNODE + 3) / 4;
    float* wav0 = wav;
    float* wav1 = wav + DIM * 8;
    float* wav2 = wav + 2 * DIM * 8;
    float* wav3 = wav + 3 * DIM * 8;

    // ---- Layer 0 ----
    transform_kernel<<<2 * TNB, 256, 0, stream>>>(
        x_food, Wsrc_fn, wav0, HS_fn, AS_fn, AD_nf,
        x_nut,  Wsrc_nf, wav1, HS_nf, AS_nf, AD_fn, Mbuf, TNB);
    agg_kernel<<<2 * ANB, 256, 0, stream>>>(
        HS_fn, AS_fn, AD_fn, ptr_fn, srcs_fn, bias_fn, B_nut,
        HS_nf, AS_nf, AD_nf, ptr_nf, srcs_nf, bias_nf, B_food, Mbuf, ANB);

    // ---- Layer 1 -> d_out ----
    transform_kernel<<<2 * TNB, 256, 0, stream>>>(
        B_food, Wsrc_fn + WL, wav2, HS_fn, AS_fn, AD_nf,
        B_nut,  Wsrc_nf + WL, wav3, HS_nf, AS_nf, AD_fn, Mbuf + 8, TNB);
    agg_kernel<<<2 * ANB, 256, 0, stream>>>(
        HS_fn, AS_fn, AD_fn, ptr_fn, srcs_fn, bias_fn + DIM, out + (size_t)NNODE * DIM,
        HS_nf, AS_nf, AD_nf, ptr_nf, srcs_nf, bias_nf + DIM, out, Mbuf + 8, ANB);
}

// Round 3
// 356.677 us; speedup vs baseline: 1.3156x; 1.1874x over previous
//
#include <hip/hip_runtime.h>
#include <math.h>

#define NNODE 50000
#define NEDGE 800000
#define DIM   128
#define NHEAD 4
#define NTILE ((NNODE + 63) / 64)   // 782
#define NBUCK 196                    // ceil(NNODE/256) coarse buckets (dst>>8)
#define ECHUNK 196                   // ceil(NEDGE/4096) edge chunks
#define CAP   6144                   // per-bucket LDS sort capacity (mean 4082)
#define LOG2E 1.44269504088896340736f

typedef __bf16 bf16x8 __attribute__((ext_vector_type(8)));
typedef float  f32x4  __attribute__((ext_vector_type(4)));
typedef float  f32x2  __attribute__((ext_vector_type(2)));

static __device__ __forceinline__ void bfsplit(float x, ushort& hi, ushort& lo) {
    __bf16 h = (__bf16)x;
    float hf = (float)h;
    __bf16 l = (__bf16)(x - hf);
    hi = __builtin_bit_cast(unsigned short, h);
    lo = __builtin_bit_cast(unsigned short, l);
}
static __device__ __forceinline__ ushort f2h(float x) {
    _Float16 h = (_Float16)x;
    return __builtin_bit_cast(unsigned short, h);
}
static __device__ __forceinline__ f32x2 up2v(unsigned u) {
    f32x2 r;
    r.x = (float)__builtin_bit_cast(_Float16, (unsigned short)(u & 0xffff));
    r.y = (float)__builtin_bit_cast(_Float16, (unsigned short)(u >> 16));
    return r;
}
// monotone float<->uint encoding for atomicMax on floats
static __device__ __forceinline__ unsigned encf(float f) {
    unsigned u = __builtin_bit_cast(unsigned, f);
    return (u >> 31) ? ~u : (u | 0x80000000u);
}
static __device__ __forceinline__ float decf(unsigned x) {
    unsigned u = (x >> 31) ? (x & 0x7fffffffu) : ~x;
    return __builtin_bit_cast(float, u);
}

// ---------------------------------------------------------------------------
// CSR build via two-level counting sort (no random 4B global scatters).
// ---------------------------------------------------------------------------
__global__ __launch_bounds__(256) void bhist(const int* __restrict__ eA,
                                             const int* __restrict__ eB,
                                             int* __restrict__ bcnt) {
    int rel = (int)(blockIdx.x >= ECHUNK);
    const int* dstrow = (rel ? eB : eA) + NEDGE;
    int blk = blockIdx.x - rel * ECHUNK;
    __shared__ int hist[256];
    hist[threadIdx.x] = 0;
    __syncthreads();
    int base = blk * 4096;
    #pragma unroll
    for (int k = 0; k < 16; k++) {
        int e = base + k * 256 + threadIdx.x;
        if (e < NEDGE) atomicAdd(&hist[dstrow[e] >> 8], 1);
    }
    __syncthreads();
    int h = hist[threadIdx.x];
    if (h) atomicAdd(&bcnt[rel * 256 + threadIdx.x], h);
}

__global__ __launch_bounds__(256) void bscan(const int* __restrict__ bcnt,
                                             int* __restrict__ bko, int* __restrict__ bcur,
                                             int* __restrict__ ptrA, int* __restrict__ ptrB) {
    int rel = blockIdx.x;
    __shared__ int tmp[256];
    int t = threadIdx.x;
    int v = bcnt[rel * 256 + t];
    tmp[t] = v; __syncthreads();
    for (int off = 1; off < 256; off <<= 1) {
        int a = (t >= off) ? tmp[t - off] : 0; __syncthreads();
        tmp[t] += a; __syncthreads();
    }
    int excl = tmp[t] - v;
    bko[rel * 256 + t] = excl;
    bcur[rel * 256 + t] = excl;
    if (t == 255) (rel ? ptrB : ptrA)[NNODE] = tmp[255];
}

__global__ __launch_bounds__(256) void bscatter(const int* __restrict__ eA,
                                                const int* __restrict__ eB,
                                                int* __restrict__ bcur,
                                                unsigned* __restrict__ bktA,
                                                unsigned* __restrict__ bktB) {
    int rel = (int)(blockIdx.x >= ECHUNK);
    const int* ebase = rel ? eB : eA;
    unsigned* bkt = rel ? bktB : bktA;
    int blk = blockIdx.x - rel * ECHUNK;
    __shared__ int hist[256], bas[256], cur[256];
    hist[threadIdx.x] = 0;
    __syncthreads();
    int base = blk * 4096;
    #pragma unroll
    for (int k = 0; k < 16; k++) {
        int e = base + k * 256 + threadIdx.x;
        if (e < NEDGE) atomicAdd(&hist[ebase[NEDGE + e] >> 8], 1);
    }
    __syncthreads();
    int h = hist[threadIdx.x];
    bas[threadIdx.x] = h ? atomicAdd(&bcur[rel * 256 + threadIdx.x], h) : 0;
    cur[threadIdx.x] = 0;
    __syncthreads();
    #pragma unroll
    for (int k = 0; k < 16; k++) {
        int e = base + k * 256 + threadIdx.x;
        if (e < NEDGE) {
            int s = ebase[e], d = ebase[NEDGE + e];
            int b = d >> 8;
            int loc = atomicAdd(&cur[b], 1);
            bkt[bas[b] + loc] = ((unsigned)(d & 255) << 16) | (unsigned)s;
        }
    }
}

// per-bucket exact sort in LDS -> coalesced srcs (ushort) + ptr for free.
__global__ __launch_bounds__(256) void bsort(const unsigned* __restrict__ bktA,
                                             const unsigned* __restrict__ bktB,
                                             const int* __restrict__ bko,
                                             int* __restrict__ ptrA, int* __restrict__ ptrB,
                                             ushort* __restrict__ srcA, ushort* __restrict__ srcB) {
    int rel = (int)(blockIdx.x >= NBUCK);
    const unsigned* bkt = rel ? bktB : bktA;
    int* ptr   = rel ? ptrB : ptrA;
    ushort* srcs = rel ? srcB : srcA;
    int b = blockIdx.x - rel * NBUCK;
    int beg = bko[rel * 256 + b], end = bko[rel * 256 + b + 1];
    int cnt_e = end - beg;
    __shared__ int hist[256], excl[256], cur[256];
    __shared__ unsigned sorted[CAP];
    int t = threadIdx.x;
    hist[t] = 0;
    __syncthreads();
    for (int i = t; i < cnt_e; i += 256) atomicAdd(&hist[bkt[beg + i] >> 16], 1);
    __syncthreads();
    int v = hist[t];
    excl[t] = v; __syncthreads();
    for (int off = 1; off < 256; off <<= 1) {
        int a = (t >= off) ? excl[t - off] : 0; __syncthreads();
        excl[t] += a; __syncthreads();
    }
    int ex = excl[t] - v;
    int d = b * 256 + t;
    if (d < NNODE) ptr[d] = beg + ex;
    cur[t] = ex;
    __syncthreads();
    for (int i = t; i < cnt_e; i += 256) {
        unsigned u = bkt[beg + i];
        int dl = u >> 16;
        int p = atomicAdd(&cur[dl], 1);
        if (p < CAP) sorted[p] = u;
        else srcs[beg + p] = (ushort)(u & 0xffffu);  // unreachable overflow path
    }
    __syncthreads();
    int lim = cnt_e < CAP ? cnt_e : CAP;
    for (int i = t; i < lim; i += 256) {
        unsigned u = sorted[i];
        srcs[beg + i] = (ushort)(u & 0xffffu);
    }
}

// ---------------------------------------------------------------------------
// wav[call][k][8]: cols 0..3 = was (Wsrc·a_src), 4..7 = wad (Wdst·a_dst)
// ---------------------------------------------------------------------------
__global__ void prep_wav(const float* __restrict__ Wsrc_fn, const float* __restrict__ a_src_fn,
                         const float* __restrict__ Wdst_fn, const float* __restrict__ a_dst_fn,
                         const float* __restrict__ Wsrc_nf, const float* __restrict__ a_src_nf,
                         const float* __restrict__ Wdst_nf, const float* __restrict__ a_dst_nf,
                         float* __restrict__ wav) {
    int call = blockIdx.x;
    int layer = call >> 1, which = call & 1;
    const float* Ws = which ? Wsrc_nf : Wsrc_fn;
    const float* as = which ? a_src_nf : a_src_fn;
    const float* Wd = which ? Wdst_fn : Wdst_nf;
    const float* ad = which ? a_dst_fn : a_dst_nf;
    Ws += layer * DIM * DIM; Wd += layer * DIM * DIM;
    as += layer * DIM; ad += layer * DIM;
    for (int it = threadIdx.x; it < 512; it += 256) {
        int k = it >> 2, h = it & 3;
        float s = 0.f, dv = 0.f;
        #pragma unroll 8
        for (int c = 0; c < 32; c++) {
            s  += Ws[k * DIM + h * 32 + c] * as[h * 32 + c];
            dv += Wd[k * DIM + h * 32 + c] * ad[h * 32 + c];
        }
        float* o = wav + (size_t)call * DIM * 8 + k * 8;
        o[h] = s; o[h + 4] = dv;
    }
}

// ---------------------------------------------------------------------------
// Transform (split-bf16 MFMA): HS(fp16) = X @ W ; [AS|AD] = X @ wav (MFMA too)
// AS/AD/max pre-scaled by log2(e) (agg uses raw exp2; lrelu is +scale-inv).
// v3: grid 2x384 (~4 tiles/block, staging amortized), register ping-pong
// prefetch of next tile's X rows, HS epilogue through an LDS transpose tile
// -> 2x dwordx4 coalesced stores/thread (was 16 scalar ushort stores/lane).
// ---------------------------------------------------------------------------
__global__ __launch_bounds__(256, 3) void transform_kernel(
    const float* __restrict__ XA, const float* __restrict__ WA, const float* __restrict__ wavA,
    ushort* __restrict__ HSA, float* __restrict__ ASA, float* __restrict__ ADA,
    const float* __restrict__ XB, const float* __restrict__ WB, const float* __restrict__ wavB,
    ushort* __restrict__ HSB, float* __restrict__ ASB, float* __restrict__ ADB,
    unsigned* __restrict__ Mg, int nb)
{
    int rel = (int)(blockIdx.x >= (unsigned)nb);
    const float* X  = rel ? XB : XA;
    const float* W  = rel ? WB : WA;
    const float* wav = rel ? wavB : wavA;
    ushort* HS = rel ? HSB : HSA;
    float*  AS = rel ? ASB : ASA;
    float*  AD = rel ? ADB : ADA;

    __shared__ ushort WTh[64][136], WTl[64][136];     // W^T[col][k] hi/lo
    __shared__ ushort wavTh[16][136], wavTl[16][136]; // wav^T[oi][k], oi>=8 zero
    __shared__ ushort hsb[64][72];                    // f16 tile transpose buffer
    __shared__ unsigned mloc[4];

    int vb = blockIdx.x - rel * nb;
    int half = vb & 1;
    int ch = half * 64;

    for (int i = threadIdx.x; i < 64 * DIM; i += 256) {
        int col = i & 63, k = i >> 6;
        ushort hi, lo; bfsplit(W[k * DIM + ch + col], hi, lo);
        WTh[col][k] = hi; WTl[col][k] = lo;
    }
    if (half == 0) {
        for (int i = threadIdx.x; i < 16 * DIM; i += 256) {
            int c = i & 15, k = i >> 4;
            float w = (c < 8) ? wav[k * 8 + c] : 0.f;
            ushort hi, lo; bfsplit(w, hi, lo);
            wavTh[c][k] = hi; wavTl[c][k] = lo;
        }
    }
    if (threadIdx.x < 4) mloc[threadIdx.x] = 0;
    __syncthreads();

    const int wv = threadIdx.x >> 6, lane = threadIdx.x & 63;
    const int lm = lane & 15, lq = lane >> 4;
    const int r0 = wv * 16;
    const int tstride = nb >> 1;

    auto loadX = [&](int tile, float4* dst) {
        int myrow = tile * 64 + r0 + lm;
        int rowc = myrow < NNODE ? myrow : NNODE - 1;   // clamp (dup is harmless)
        const float4* Xr = (const float4*)(X + (size_t)rowc * DIM);
        #pragma unroll
        for (int kc = 0; kc < 4; kc++) {
            dst[kc * 2]     = Xr[kc * 8 + lq * 2];
            dst[kc * 2 + 1] = Xr[kc * 8 + lq * 2 + 1];
        }
    };

    auto computeTile = [&](const float4* xv, int tile) {
        int row0 = tile * 64;
        f32x4 acc[4] = {{0,0,0,0},{0,0,0,0},{0,0,0,0},{0,0,0,0}};
        f32x4 accv = {0,0,0,0};
        #pragma unroll
        for (int kc = 0; kc < 4; kc++) {
            const float* fp = (const float*)&xv[kc * 2];
            bf16x8 ah, al;
            #pragma unroll
            for (int j = 0; j < 8; j++) {
                float x = fp[j];
                __bf16 h = (__bf16)x;
                ah[j] = h;
                al[j] = (__bf16)(x - (float)h);
            }
            int k0 = kc * 32 + lq * 8;
            #pragma unroll
            for (int ct = 0; ct < 4; ct++) {
                bf16x8 bh = *(const bf16x8*)&WTh[ct * 16 + lm][k0];
                bf16x8 bl = *(const bf16x8*)&WTl[ct * 16 + lm][k0];
                acc[ct] = __builtin_amdgcn_mfma_f32_16x16x32_bf16(al, bh, acc[ct], 0, 0, 0);
                acc[ct] = __builtin_amdgcn_mfma_f32_16x16x32_bf16(ah, bl, acc[ct], 0, 0, 0);
                acc[ct] = __builtin_amdgcn_mfma_f32_16x16x32_bf16(ah, bh, acc[ct], 0, 0, 0);
            }
            if (half == 0) {
                bf16x8 vh = *(const bf16x8*)&wavTh[lm][k0];
                bf16x8 vl = *(const bf16x8*)&wavTl[lm][k0];
                accv = __builtin_amdgcn_mfma_f32_16x16x32_bf16(al, vh, accv, 0, 0, 0);
                accv = __builtin_amdgcn_mfma_f32_16x16x32_bf16(ah, vl, accv, 0, 0, 0);
                accv = __builtin_amdgcn_mfma_f32_16x16x32_bf16(ah, vh, accv, 0, 0, 0);
            }
        }

        // AS/AD stores (half-0 blocks only); lanes lm<8 hold the 8 outputs
        if (half == 0 && lm < 8) {
            accv *= LOG2E;   // pre-scale so agg uses exp2 directly
            float mx4 = -INFINITY;
            #pragma unroll
            for (int r = 0; r < 4; r++) {
                int row = row0 + r0 + lq * 4 + r;
                if (row < NNODE) {
                    if (lm < 4) AS[row * 4 + lm] = accv[r];
                    else        AD[row * 4 + (lm - 4)] = accv[r];
                }
                mx4 = fmaxf(mx4, accv[r]);
            }
            if (lm < 4) atomicMax(&mloc[lm], encf(mx4));
        }

        // HS epilogue: fragments -> LDS transpose tile -> coalesced stores
        __syncthreads();   // hsb free (previous tile's reads done)
        #pragma unroll
        for (int ct = 0; ct < 4; ct++) {
            #pragma unroll
            for (int r = 0; r < 4; r++)
                hsb[r0 + lq * 4 + r][ct * 16 + lm] = f2h(acc[ct][r]);
        }
        __syncthreads();
        #pragma unroll
        for (int p = 0; p < 2; p++) {
            int idx = p * 256 + (int)threadIdx.x;
            int lr = idx >> 3, off = (idx & 7) * 8;
            int rg = row0 + lr;
            if (rg < NNODE)
                *(uint4*)(HS + (size_t)rg * DIM + ch + off) = *(const uint4*)&hsb[lr][off];
        }
    };

    float4 xa[8], xb[8];
    int tile = vb >> 1;
    loadX(tile, xa);
    while (tile < NTILE) {
        if (tile + tstride < NTILE) loadX(tile + tstride, xb);
        computeTile(xa, tile);
        tile += tstride;
        if (tile >= NTILE) break;
        if (tile + tstride < NTILE) loadX(tile + tstride, xa);
        computeTile(xb, tile);
        tile += tstride;
    }

    __syncthreads();
    if (half == 0 && threadIdx.x < 4)
        atomicMax(&Mg[rel * 4 + threadIdx.x], mloc[threadIdx.x]);
}

// ---------------------------------------------------------------------------
// Fused aggregation, quarter-wave edge slots: one wave per dst node; each
// group of 16 lanes owns one edge (4 edges in flight per wave-instruction),
// each lane owns 8 channels (one uint4 = 8 f16 of the HS row). Alpha math
// runs once per edge-slot instead of replicated 16x. Cross-quarter butterfly
// at the end combines the 4 edge streams. Fuses softmax-normalize+bias+ELU.
// ---------------------------------------------------------------------------
__global__ __launch_bounds__(256) void agg_kernel(
    const ushort* __restrict__ HSA, const float* __restrict__ ASA, const float* __restrict__ ADA,
    const int* __restrict__ ptrA, const ushort* __restrict__ srcA,
    const float* __restrict__ biasA, float* __restrict__ outA,
    const ushort* __restrict__ HSB, const float* __restrict__ ASB, const float* __restrict__ ADB,
    const int* __restrict__ ptrB, const ushort* __restrict__ srcB,
    const float* __restrict__ biasB, float* __restrict__ outB,
    const unsigned* __restrict__ Mg, int nb)
{
    int rel = (int)(blockIdx.x >= (unsigned)nb);
    const uint4* HS4 = (const uint4*)(rel ? HSB : HSA);   // row = 16 uint4
    const float* AS = rel ? ASB : ASA;
    const float* AD = rel ? ADB : ADA;
    const ushort* srcs = rel ? srcB : srcA;
    const int* ptr = rel ? ptrB : ptrA;
    const float* bias = rel ? biasB : biasA;
    float* out = rel ? outB : outA;

    int bid = blockIdx.x - rel * nb;
    int wave = threadIdx.x >> 6, lane = threadIdx.x & 63;
    int d = bid * 4 + wave;
    if (d >= NNODE) return;

    int q  = lane >> 4;        // edge slot 0..3
    int li = lane & 15;        // channel block: channels li*8 .. li*8+7
    int hh = li >> 2;          // head of this channel block

    float ad_h = AD[d * 4 + hh];
    float mm = decf(Mg[rel * 4 + hh]) + ad_h;
    mm = mm > 0.f ? mm : 0.2f * mm;

    int e0 = ptr[d], e1 = ptr[d + 1];

    float acc[8] = {0.f,0.f,0.f,0.f,0.f,0.f,0.f,0.f};
    float l = 0.f;

    int e = e0;
    for (; e + 8 <= e1; e += 8) {           // 2 slots/iter, both fully active
        int iA = e + q, iB = e + 4 + q;
        int sA = srcs[iA], sB = srcs[iB];
        uint4 hA = HS4[sA * 16 + li];
        uint4 hB = HS4[sB * 16 + li];
        float aA = AS[sA * 4 + hh];
        float aB = AS[sB * 4 + hh];
        float vA = aA + ad_h; vA = fmaxf(vA, 0.2f * vA);
        float vB = aB + ad_h; vB = fmaxf(vB, 0.2f * vB);
        float pA = __builtin_amdgcn_exp2f(vA - mm);
        float pB = __builtin_amdgcn_exp2f(vB - mm);
        l += pA + pB;
        #pragma unroll
        for (int j = 0; j < 4; j++) {
            f32x2 h2A = up2v(((const unsigned*)&hA)[j]);
            f32x2 h2B = up2v(((const unsigned*)&hB)[j]);
            acc[2*j]   += h2A.x * pA + h2B.x * pB;
            acc[2*j+1] += h2A.y * pA + h2B.y * pB;
        }
    }
    for (; e < e1; e += 4) {                // predicated tail (<= 2 iters)
        int ee = e + q;
        bool act = ee < e1;
        int eidx = act ? ee : e1 - 1;
        int s = srcs[eidx];
        uint4 hv = HS4[s * 16 + li];
        float av = AS[s * 4 + hh];
        float v = av + ad_h; v = fmaxf(v, 0.2f * v);
        float p = __builtin_amdgcn_exp2f(v - mm);
        p = act ? p : 0.f;
        l += p;
        #pragma unroll
        for (int j = 0; j < 4; j++) {
            f32x2 h2 = up2v(((const unsigned*)&hv)[j]);
            acc[2*j]   += h2.x * p;
            acc[2*j+1] += h2.y * p;
        }
    }

    // combine the 4 edge-slot streams (lanes with equal li, differing q)
    #pragma unroll
    for (int j = 0; j < 8; j++) {
        acc[j] += __shfl_xor(acc[j], 16, 64);
        acc[j] += __shfl_xor(acc[j], 32, 64);
    }
    l += __shfl_xor(l, 16, 64);
    l += __shfl_xor(l, 32, 64);

    if (q == 0) {
        float inv = 1.f / (l + 1e-16f);
        const float4* b4 = (const float4*)bias + li * 2;
        float4 b0 = b4[0], b1 = b4[1];
        float o[8];
        o[0] = acc[0] * inv + b0.x; o[1] = acc[1] * inv + b0.y;
        o[2] = acc[2] * inv + b0.z; o[3] = acc[3] * inv + b0.w;
        o[4] = acc[4] * inv + b1.x; o[5] = acc[5] * inv + b1.y;
        o[6] = acc[6] * inv + b1.z; o[7] = acc[7] * inv + b1.w;
        #pragma unroll
        for (int j = 0; j < 8; j++)
            o[j] = o[j] > 0.f ? o[j] : __expf(o[j]) - 1.f;   // ELU
        float4* o4 = (float4*)(out + (size_t)d * DIM) + li * 2;
        o4[0] = make_float4(o[0], o[1], o[2], o[3]);
        o4[1] = make_float4(o[4], o[5], o[6], o[7]);
    }
}

// ---------------------------------------------------------------------------
extern "C" void kernel_launch(void* const* d_in, const int* in_sizes, int n_in,
                              void* d_out, int out_size, void* d_ws, size_t ws_size,
                              hipStream_t stream) {
    const float* x_food      = (const float*)d_in[0];
    const float* x_nut       = (const float*)d_in[1];
    const float* Wsrc_fn     = (const float*)d_in[2];
    const float* Wdst_fn     = (const float*)d_in[3];
    const float* att_src_fn  = (const float*)d_in[4];
    const float* att_dst_fn  = (const float*)d_in[5];
    const float* bias_fn     = (const float*)d_in[6];
    const float* Wsrc_nf     = (const float*)d_in[7];
    const float* Wdst_nf     = (const float*)d_in[8];
    const float* att_src_nf  = (const float*)d_in[9];
    const float* att_dst_nf  = (const float*)d_in[10];
    const float* bias_nf     = (const float*)d_in[11];
    const int*   ei_fn       = (const int*)d_in[12];
    const int*   ei_nf       = (const int*)d_in[13];
    float* out = (float*)d_out;

    char* ws = (char*)d_ws;
    size_t off = 0;
    auto alloc_f = [&](size_t n) { float* p = (float*)(ws + off); off += n * 4; return p; };
    auto alloc_i = [&](size_t n) { int* p = (int*)(ws + off); off += n * 4; return p; };
    auto alloc_u = [&](size_t n) { ushort* p = (ushort*)(ws + off); off += n * 2; return p; };

    float* B_food = alloc_f((size_t)NNODE * DIM);
    float* B_nut  = alloc_f((size_t)NNODE * DIM);
    ushort* HS_fn = alloc_u((size_t)NNODE * DIM);
    ushort* HS_nf = alloc_u((size_t)NNODE * DIM);
    float* AS_fn  = alloc_f(NNODE * NHEAD);
    float* AS_nf  = alloc_f(NNODE * NHEAD);
    float* AD_fn  = alloc_f(NNODE * NHEAD);
    float* AD_nf  = alloc_f(NNODE * NHEAD);
    float* wav    = alloc_f(4 * DIM * 8);
    int* ptr_fn   = alloc_i(50004);
    int* ptr_nf   = alloc_i(50004);
    ushort* srcs_fn = alloc_u(NEDGE);
    ushort* srcs_nf = alloc_u(NEDGE);
    int* bcnt     = alloc_i(512);
    unsigned* Mbuf = (unsigned*)alloc_i(16);   // [layer][rel][head]
    int* bko      = alloc_i(512);
    int* bcur     = alloc_i(512);
    // bkt buffers alias B_food/B_nut (dead until after CSR build)
    unsigned* bkt_fn = (unsigned*)B_food;
    unsigned* bkt_nf = (unsigned*)B_nut;

    // ---- CSR build: two-level counting sort (+ zero Mbuf, contiguous) ----
    hipMemsetAsync(bcnt, 0, (512 + 16) * 4, stream);
    bhist<<<2 * ECHUNK, 256, 0, stream>>>(ei_fn, ei_nf, bcnt);
    bscan<<<2, 256, 0, stream>>>(bcnt, bko, bcur, ptr_fn, ptr_nf);
    bscatter<<<2 * ECHUNK, 256, 0, stream>>>(ei_fn, ei_nf, bcur, bkt_fn, bkt_nf);
    bsort<<<2 * NBUCK, 256, 0, stream>>>(bkt_fn, bkt_nf, bko, ptr_fn, ptr_nf,
                                         srcs_fn, srcs_nf);

    prep_wav<<<4, 256, 0, stream>>>(Wsrc_fn, att_src_fn, Wdst_fn, att_dst_fn,
                                    Wsrc_nf, att_src_nf, Wdst_nf, att_dst_nf, wav);

    const int WL = DIM * DIM;
    const int TNB = 384;
    const int ANB = (NNODE + 3) / 4;
    float* wav0 = wav;
    float* wav1 = wav + DIM * 8;
    float* wav2 = wav + 2 * DIM * 8;
    float* wav3 = wav + 3 * DIM * 8;

    // ---- Layer 0 ----
    transform_kernel<<<2 * TNB, 256, 0, stream>>>(
        x_food, Wsrc_fn, wav0, HS_fn, AS_fn, AD_nf,
        x_nut,  Wsrc_nf, wav1, HS_nf, AS_nf, AD_fn, Mbuf, TNB);
    agg_kernel<<<2 * ANB, 256, 0, stream>>>(
        HS_fn, AS_fn, AD_fn, ptr_fn, srcs_fn, bias_fn, B_nut,
        HS_nf, AS_nf, AD_nf, ptr_nf, srcs_nf, bias_nf, B_food, Mbuf, ANB);

    // ---- Layer 1 -> d_out ----
    transform_kernel<<<2 * TNB, 256, 0, stream>>>(
        B_food, Wsrc_fn + WL, wav2, HS_fn, AS_fn, AD_nf,
        B_nut,  Wsrc_nf + WL, wav3, HS_nf, AS_nf, AD_fn, Mbuf + 8, TNB);
    agg_kernel<<<2 * ANB, 256, 0, stream>>>(
        HS_fn, AS_fn, AD_fn, ptr_fn, srcs_fn, bias_fn + DIM, out + (size_t)NNODE * DIM,
        HS_nf, AS_nf, AD_nf, ptr_nf, srcs_nf, bias_nf + DIM, out, Mbuf + 8, ANB);
}

// Round 4
// 356.176 us; speedup vs baseline: 1.3174x; 1.0014x over previous
//
#include <hip/hip_runtime.h>
#include <math.h>

#define NNODE 50000
#define NEDGE 800000
#define DIM   128
#define NHEAD 4
#define NTILE ((NNODE + 63) / 64)   // 782
#define NBUCK 196                    // ceil(NNODE/256) coarse buckets (dst>>8)
#define ECHUNK 196                   // ceil(NEDGE/4096) edge chunks
#define CAP   6144                   // per-bucket LDS sort capacity (mean 4082)
#define LOG2E 1.44269504088896340736f

typedef __bf16 bf16x8 __attribute__((ext_vector_type(8)));
typedef float  f32x4  __attribute__((ext_vector_type(4)));
typedef float  f32x2  __attribute__((ext_vector_type(2)));
typedef _Float16 f16x8 __attribute__((ext_vector_type(8)));

static __device__ __forceinline__ void bfsplit(float x, ushort& hi, ushort& lo) {
    __bf16 h = (__bf16)x;
    float hf = (float)h;
    __bf16 l = (__bf16)(x - hf);
    hi = __builtin_bit_cast(unsigned short, h);
    lo = __builtin_bit_cast(unsigned short, l);
}
static __device__ __forceinline__ ushort f2h(float x) {
    _Float16 h = (_Float16)x;
    return __builtin_bit_cast(unsigned short, h);
}
// monotone float<->uint encoding for atomicMax on floats
static __device__ __forceinline__ unsigned encf(float f) {
    unsigned u = __builtin_bit_cast(unsigned, f);
    return (u >> 31) ? ~u : (u | 0x80000000u);
}
static __device__ __forceinline__ float decf(unsigned x) {
    unsigned u = (x >> 31) ? (x & 0x7fffffffu) : ~x;
    return __builtin_bit_cast(float, u);
}

// ---------------------------------------------------------------------------
// CSR build via two-level counting sort (no random 4B global scatters).
// ---------------------------------------------------------------------------
__global__ __launch_bounds__(256) void bhist(const int* __restrict__ eA,
                                             const int* __restrict__ eB,
                                             int* __restrict__ bcnt) {
    int rel = (int)(blockIdx.x >= ECHUNK);
    const int* dstrow = (rel ? eB : eA) + NEDGE;
    int blk = blockIdx.x - rel * ECHUNK;
    __shared__ int hist[256];
    hist[threadIdx.x] = 0;
    __syncthreads();
    int base = blk * 4096;
    #pragma unroll
    for (int k = 0; k < 16; k++) {
        int e = base + k * 256 + threadIdx.x;
        if (e < NEDGE) atomicAdd(&hist[dstrow[e] >> 8], 1);
    }
    __syncthreads();
    int h = hist[threadIdx.x];
    if (h) atomicAdd(&bcnt[rel * 256 + threadIdx.x], h);
}

__global__ __launch_bounds__(256) void bscan(const int* __restrict__ bcnt,
                                             int* __restrict__ bko, int* __restrict__ bcur,
                                             int* __restrict__ ptrA, int* __restrict__ ptrB) {
    int rel = blockIdx.x;
    __shared__ int tmp[256];
    int t = threadIdx.x;
    int v = bcnt[rel * 256 + t];
    tmp[t] = v; __syncthreads();
    for (int off = 1; off < 256; off <<= 1) {
        int a = (t >= off) ? tmp[t - off] : 0; __syncthreads();
        tmp[t] += a; __syncthreads();
    }
    int excl = tmp[t] - v;
    bko[rel * 256 + t] = excl;
    bcur[rel * 256 + t] = excl;
    if (t == 255) (rel ? ptrB : ptrA)[NNODE] = tmp[255];
}

__global__ __launch_bounds__(256) void bscatter(const int* __restrict__ eA,
                                                const int* __restrict__ eB,
                                                int* __restrict__ bcur,
                                                unsigned* __restrict__ bktA,
                                                unsigned* __restrict__ bktB) {
    int rel = (int)(blockIdx.x >= ECHUNK);
    const int* ebase = rel ? eB : eA;
    unsigned* bkt = rel ? bktB : bktA;
    int blk = blockIdx.x - rel * ECHUNK;
    __shared__ int hist[256], bas[256], cur[256];
    hist[threadIdx.x] = 0;
    __syncthreads();
    int base = blk * 4096;
    #pragma unroll
    for (int k = 0; k < 16; k++) {
        int e = base + k * 256 + threadIdx.x;
        if (e < NEDGE) atomicAdd(&hist[ebase[NEDGE + e] >> 8], 1);
    }
    __syncthreads();
    int h = hist[threadIdx.x];
    bas[threadIdx.x] = h ? atomicAdd(&bcur[rel * 256 + threadIdx.x], h) : 0;
    cur[threadIdx.x] = 0;
    __syncthreads();
    #pragma unroll
    for (int k = 0; k < 16; k++) {
        int e = base + k * 256 + threadIdx.x;
        if (e < NEDGE) {
            int s = ebase[e], d = ebase[NEDGE + e];
            int b = d >> 8;
            int loc = atomicAdd(&cur[b], 1);
            bkt[bas[b] + loc] = ((unsigned)(d & 255) << 16) | (unsigned)s;
        }
    }
}

// per-bucket exact sort in LDS -> coalesced srcs (ushort) + ptr for free.
__global__ __launch_bounds__(256) void bsort(const unsigned* __restrict__ bktA,
                                             const unsigned* __restrict__ bktB,
                                             const int* __restrict__ bko,
                                             int* __restrict__ ptrA, int* __restrict__ ptrB,
                                             ushort* __restrict__ srcA, ushort* __restrict__ srcB) {
    int rel = (int)(blockIdx.x >= NBUCK);
    const unsigned* bkt = rel ? bktB : bktA;
    int* ptr   = rel ? ptrB : ptrA;
    ushort* srcs = rel ? srcB : srcA;
    int b = blockIdx.x - rel * NBUCK;
    int beg = bko[rel * 256 + b], end = bko[rel * 256 + b + 1];
    int cnt_e = end - beg;
    __shared__ int hist[256], excl[256], cur[256];
    __shared__ unsigned sorted[CAP];
    int t = threadIdx.x;
    hist[t] = 0;
    __syncthreads();
    for (int i = t; i < cnt_e; i += 256) atomicAdd(&hist[bkt[beg + i] >> 16], 1);
    __syncthreads();
    int v = hist[t];
    excl[t] = v; __syncthreads();
    for (int off = 1; off < 256; off <<= 1) {
        int a = (t >= off) ? excl[t - off] : 0; __syncthreads();
        excl[t] += a; __syncthreads();
    }
    int ex = excl[t] - v;
    int d = b * 256 + t;
    if (d < NNODE) ptr[d] = beg + ex;
    cur[t] = ex;
    __syncthreads();
    for (int i = t; i < cnt_e; i += 256) {
        unsigned u = bkt[beg + i];
        int dl = u >> 16;
        int p = atomicAdd(&cur[dl], 1);
        if (p < CAP) sorted[p] = u;
        else srcs[beg + p] = (ushort)(u & 0xffffu);  // unreachable overflow path
    }
    __syncthreads();
    int lim = cnt_e < CAP ? cnt_e : CAP;
    for (int i = t; i < lim; i += 256) {
        unsigned u = sorted[i];
        srcs[beg + i] = (ushort)(u & 0xffffu);
    }
}

// ---------------------------------------------------------------------------
// wav[call][k][8]: cols 0..3 = was (Wsrc·a_src), 4..7 = wad (Wdst·a_dst)
// ---------------------------------------------------------------------------
__global__ void prep_wav(const float* __restrict__ Wsrc_fn, const float* __restrict__ a_src_fn,
                         const float* __restrict__ Wdst_fn, const float* __restrict__ a_dst_fn,
                         const float* __restrict__ Wsrc_nf, const float* __restrict__ a_src_nf,
                         const float* __restrict__ Wdst_nf, const float* __restrict__ a_dst_nf,
                         float* __restrict__ wav) {
    int call = blockIdx.x;
    int layer = call >> 1, which = call & 1;
    const float* Ws = which ? Wsrc_nf : Wsrc_fn;
    const float* as = which ? a_src_nf : a_src_fn;
    const float* Wd = which ? Wdst_fn : Wdst_nf;
    const float* ad = which ? a_dst_fn : a_dst_nf;
    Ws += layer * DIM * DIM; Wd += layer * DIM * DIM;
    as += layer * DIM; ad += layer * DIM;
    for (int it = threadIdx.x; it < 512; it += 256) {
        int k = it >> 2, h = it & 3;
        float s = 0.f, dv = 0.f;
        #pragma unroll 8
        for (int c = 0; c < 32; c++) {
            s  += Ws[k * DIM + h * 32 + c] * as[h * 32 + c];
            dv += Wd[k * DIM + h * 32 + c] * ad[h * 32 + c];
        }
        float* o = wav + (size_t)call * DIM * 8 + k * 8;
        o[h] = s; o[h + 4] = dv;
    }
}

// ---------------------------------------------------------------------------
// Transform (split-bf16 MFMA): HS(fp16) = X @ W ; [AS|AD] = X @ wav (MFMA too)
// AS/AD/max pre-scaled by log2(e) (agg uses raw exp2; lrelu is +scale-inv).
// grid 2x384, register ping-pong prefetch, LDS-transposed coalesced HS stores.
// ---------------------------------------------------------------------------
__global__ __launch_bounds__(256, 3) void transform_kernel(
    const float* __restrict__ XA, const float* __restrict__ WA, const float* __restrict__ wavA,
    ushort* __restrict__ HSA, float* __restrict__ ASA, float* __restrict__ ADA,
    const float* __restrict__ XB, const float* __restrict__ WB, const float* __restrict__ wavB,
    ushort* __restrict__ HSB, float* __restrict__ ASB, float* __restrict__ ADB,
    unsigned* __restrict__ Mg, int nb)
{
    int rel = (int)(blockIdx.x >= (unsigned)nb);
    const float* X  = rel ? XB : XA;
    const float* W  = rel ? WB : WA;
    const float* wav = rel ? wavB : wavA;
    ushort* HS = rel ? HSB : HSA;
    float*  AS = rel ? ASB : ASA;
    float*  AD = rel ? ADB : ADA;

    __shared__ ushort WTh[64][136], WTl[64][136];     // W^T[col][k] hi/lo
    __shared__ ushort wavTh[16][136], wavTl[16][136]; // wav^T[oi][k], oi>=8 zero
    __shared__ ushort hsb[64][72];                    // f16 tile transpose buffer
    __shared__ unsigned mloc[4];

    int vb = blockIdx.x - rel * nb;
    int half = vb & 1;
    int ch = half * 64;

    for (int i = threadIdx.x; i < 64 * DIM; i += 256) {
        int col = i & 63, k = i >> 6;
        ushort hi, lo; bfsplit(W[k * DIM + ch + col], hi, lo);
        WTh[col][k] = hi; WTl[col][k] = lo;
    }
    if (half == 0) {
        for (int i = threadIdx.x; i < 16 * DIM; i += 256) {
            int c = i & 15, k = i >> 4;
            float w = (c < 8) ? wav[k * 8 + c] : 0.f;
            ushort hi, lo; bfsplit(w, hi, lo);
            wavTh[c][k] = hi; wavTl[c][k] = lo;
        }
    }
    if (threadIdx.x < 4) mloc[threadIdx.x] = 0;
    __syncthreads();

    const int wv = threadIdx.x >> 6, lane = threadIdx.x & 63;
    const int lm = lane & 15, lq = lane >> 4;
    const int r0 = wv * 16;
    const int tstride = nb >> 1;

    auto loadX = [&](int tile, float4* dst) {
        int myrow = tile * 64 + r0 + lm;
        int rowc = myrow < NNODE ? myrow : NNODE - 1;   // clamp (dup is harmless)
        const float4* Xr = (const float4*)(X + (size_t)rowc * DIM);
        #pragma unroll
        for (int kc = 0; kc < 4; kc++) {
            dst[kc * 2]     = Xr[kc * 8 + lq * 2];
            dst[kc * 2 + 1] = Xr[kc * 8 + lq * 2 + 1];
        }
    };

    auto computeTile = [&](const float4* xv, int tile) {
        int row0 = tile * 64;
        f32x4 acc[4] = {{0,0,0,0},{0,0,0,0},{0,0,0,0},{0,0,0,0}};
        f32x4 accv = {0,0,0,0};
        #pragma unroll
        for (int kc = 0; kc < 4; kc++) {
            const float* fp = (const float*)&xv[kc * 2];
            bf16x8 ah, al;
            #pragma unroll
            for (int j = 0; j < 8; j++) {
                float x = fp[j];
                __bf16 h = (__bf16)x;
                ah[j] = h;
                al[j] = (__bf16)(x - (float)h);
            }
            int k0 = kc * 32 + lq * 8;
            #pragma unroll
            for (int ct = 0; ct < 4; ct++) {
                bf16x8 bh = *(const bf16x8*)&WTh[ct * 16 + lm][k0];
                bf16x8 bl = *(const bf16x8*)&WTl[ct * 16 + lm][k0];
                acc[ct] = __builtin_amdgcn_mfma_f32_16x16x32_bf16(al, bh, acc[ct], 0, 0, 0);
                acc[ct] = __builtin_amdgcn_mfma_f32_16x16x32_bf16(ah, bl, acc[ct], 0, 0, 0);
                acc[ct] = __builtin_amdgcn_mfma_f32_16x16x32_bf16(ah, bh, acc[ct], 0, 0, 0);
            }
            if (half == 0) {
                bf16x8 vh = *(const bf16x8*)&wavTh[lm][k0];
                bf16x8 vl = *(const bf16x8*)&wavTl[lm][k0];
                accv = __builtin_amdgcn_mfma_f32_16x16x32_bf16(al, vh, accv, 0, 0, 0);
                accv = __builtin_amdgcn_mfma_f32_16x16x32_bf16(ah, vl, accv, 0, 0, 0);
                accv = __builtin_amdgcn_mfma_f32_16x16x32_bf16(ah, vh, accv, 0, 0, 0);
            }
        }

        // AS/AD stores (half-0 blocks only); lanes lm<8 hold the 8 outputs
        if (half == 0 && lm < 8) {
            accv *= LOG2E;   // pre-scale so agg uses exp2 directly
            float mx4 = -INFINITY;
            #pragma unroll
            for (int r = 0; r < 4; r++) {
                int row = row0 + r0 + lq * 4 + r;
                if (row < NNODE) {
                    if (lm < 4) AS[row * 4 + lm] = accv[r];
                    else        AD[row * 4 + (lm - 4)] = accv[r];
                }
                mx4 = fmaxf(mx4, accv[r]);
            }
            if (lm < 4) atomicMax(&mloc[lm], encf(mx4));
        }

        // HS epilogue: fragments -> LDS transpose tile -> coalesced stores
        __syncthreads();   // hsb free (previous tile's reads done)
        #pragma unroll
        for (int ct = 0; ct < 4; ct++) {
            #pragma unroll
            for (int r = 0; r < 4; r++)
                hsb[r0 + lq * 4 + r][ct * 16 + lm] = f2h(acc[ct][r]);
        }
        __syncthreads();
        #pragma unroll
        for (int p = 0; p < 2; p++) {
            int idx = p * 256 + (int)threadIdx.x;
            int lr = idx >> 3, off = (idx & 7) * 8;
            int rg = row0 + lr;
            if (rg < NNODE)
                *(uint4*)(HS + (size_t)rg * DIM + ch + off) = *(const uint4*)&hsb[lr][off];
        }
    };

    float4 xa[8], xb[8];
    int tile = vb >> 1;
    loadX(tile, xa);
    while (tile < NTILE) {
        if (tile + tstride < NTILE) loadX(tile + tstride, xb);
        computeTile(xa, tile);
        tile += tstride;
        if (tile >= NTILE) break;
        if (tile + tstride < NTILE) loadX(tile + tstride, xa);
        computeTile(xb, tile);
        tile += tstride;
    }

    __syncthreads();
    if (half == 0 && threadIdx.x < 4)
        atomicMax(&Mg[rel * 4 + threadIdx.x], mloc[threadIdx.x]);
}

// ---------------------------------------------------------------------------
// Fused aggregation, quarter-wave edge slots. v4: 16-edge main loop (4
// independent gather chains in flight) and v_fma_mix-style accumulation
// (f16 operand folded into the f32 FMA -> no separate cvt ops).
// ---------------------------------------------------------------------------
__global__ __launch_bounds__(256) void agg_kernel(
    const ushort* __restrict__ HSA, const float* __restrict__ ASA, const float* __restrict__ ADA,
    const int* __restrict__ ptrA, const ushort* __restrict__ srcA,
    const float* __restrict__ biasA, float* __restrict__ outA,
    const ushort* __restrict__ HSB, const float* __restrict__ ASB, const float* __restrict__ ADB,
    const int* __restrict__ ptrB, const ushort* __restrict__ srcB,
    const float* __restrict__ biasB, float* __restrict__ outB,
    const unsigned* __restrict__ Mg, int nb)
{
    int rel = (int)(blockIdx.x >= (unsigned)nb);
    const uint4* HS4 = (const uint4*)(rel ? HSB : HSA);   // row = 16 uint4
    const float* AS = rel ? ASB : ASA;
    const float* AD = rel ? ADB : ADA;
    const ushort* srcs = rel ? srcB : srcA;
    const int* ptr = rel ? ptrB : ptrA;
    const float* bias = rel ? biasB : biasA;
    float* out = rel ? outB : outA;

    int bid = blockIdx.x - rel * nb;
    int wave = threadIdx.x >> 6, lane = threadIdx.x & 63;
    int d = bid * 4 + wave;
    if (d >= NNODE) return;

    int q  = lane >> 4;        // edge slot 0..3
    int li = lane & 15;        // channel block: channels li*8 .. li*8+7
    int hh = li >> 2;          // head of this channel block

    float ad_h = AD[d * 4 + hh];
    float mm = decf(Mg[rel * 4 + hh]) + ad_h;
    mm = mm > 0.f ? mm : 0.2f * mm;

    int e0 = ptr[d], e1 = ptr[d + 1];

    float acc[8] = {0.f,0.f,0.f,0.f,0.f,0.f,0.f,0.f};
    float l = 0.f;

    int e = e0;
    // main loop: 16 edges / iter, 4 independent gather chains
    for (; e + 16 <= e1; e += 16) {
        int s0 = srcs[e + q], s1 = srcs[e + 4 + q];
        int s2 = srcs[e + 8 + q], s3 = srcs[e + 12 + q];
        uint4 u0 = HS4[s0 * 16 + li];
        uint4 u1 = HS4[s1 * 16 + li];
        uint4 u2 = HS4[s2 * 16 + li];
        uint4 u3 = HS4[s3 * 16 + li];
        float a0 = AS[s0 * 4 + hh], a1 = AS[s1 * 4 + hh];
        float a2 = AS[s2 * 4 + hh], a3 = AS[s3 * 4 + hh];
        float v0 = a0 + ad_h; v0 = fmaxf(v0, 0.2f * v0);
        float v1 = a1 + ad_h; v1 = fmaxf(v1, 0.2f * v1);
        float v2 = a2 + ad_h; v2 = fmaxf(v2, 0.2f * v2);
        float v3 = a3 + ad_h; v3 = fmaxf(v3, 0.2f * v3);
        float p0 = __builtin_amdgcn_exp2f(v0 - mm);
        float p1 = __builtin_amdgcn_exp2f(v1 - mm);
        float p2 = __builtin_amdgcn_exp2f(v2 - mm);
        float p3 = __builtin_amdgcn_exp2f(v3 - mm);
        l += (p0 + p1) + (p2 + p3);
        f16x8 h0 = __builtin_bit_cast(f16x8, u0);
        f16x8 h1 = __builtin_bit_cast(f16x8, u1);
        f16x8 h2 = __builtin_bit_cast(f16x8, u2);
        f16x8 h3 = __builtin_bit_cast(f16x8, u3);
        #pragma unroll
        for (int j = 0; j < 8; j++) {
            acc[j] += (float)h0[j] * p0;
            acc[j] += (float)h1[j] * p1;
            acc[j] += (float)h2[j] * p2;
            acc[j] += (float)h3[j] * p3;
        }
    }
    for (; e + 8 <= e1; e += 8) {
        int s0 = srcs[e + q], s1 = srcs[e + 4 + q];
        uint4 u0 = HS4[s0 * 16 + li];
        uint4 u1 = HS4[s1 * 16 + li];
        float a0 = AS[s0 * 4 + hh], a1 = AS[s1 * 4 + hh];
        float v0 = a0 + ad_h; v0 = fmaxf(v0, 0.2f * v0);
        float v1 = a1 + ad_h; v1 = fmaxf(v1, 0.2f * v1);
        float p0 = __builtin_amdgcn_exp2f(v0 - mm);
        float p1 = __builtin_amdgcn_exp2f(v1 - mm);
        l += p0 + p1;
        f16x8 h0 = __builtin_bit_cast(f16x8, u0);
        f16x8 h1 = __builtin_bit_cast(f16x8, u1);
        #pragma unroll
        for (int j = 0; j < 8; j++) {
            acc[j] += (float)h0[j] * p0;
            acc[j] += (float)h1[j] * p1;
        }
    }
    for (; e < e1; e += 4) {                // predicated tail (<= 2 iters)
        int ee = e + q;
        bool act = ee < e1;
        int eidx = act ? ee : e1 - 1;
        int s = srcs[eidx];
        uint4 uv = HS4[s * 16 + li];
        float av = AS[s * 4 + hh];
        float v = av + ad_h; v = fmaxf(v, 0.2f * v);
        float p = __builtin_amdgcn_exp2f(v - mm);
        p = act ? p : 0.f;
        l += p;
        f16x8 hv = __builtin_bit_cast(f16x8, uv);
        #pragma unroll
        for (int j = 0; j < 8; j++)
            acc[j] += (float)hv[j] * p;
    }

    // combine the 4 edge-slot streams (lanes with equal li, differing q)
    #pragma unroll
    for (int j = 0; j < 8; j++) {
        acc[j] += __shfl_xor(acc[j], 16, 64);
        acc[j] += __shfl_xor(acc[j], 32, 64);
    }
    l += __shfl_xor(l, 16, 64);
    l += __shfl_xor(l, 32, 64);

    if (q == 0) {
        float inv = 1.f / (l + 1e-16f);
        const float4* b4 = (const float4*)bias + li * 2;
        float4 b0 = b4[0], b1 = b4[1];
        float o[8];
        o[0] = acc[0] * inv + b0.x; o[1] = acc[1] * inv + b0.y;
        o[2] = acc[2] * inv + b0.z; o[3] = acc[3] * inv + b0.w;
        o[4] = acc[4] * inv + b1.x; o[5] = acc[5] * inv + b1.y;
        o[6] = acc[6] * inv + b1.z; o[7] = acc[7] * inv + b1.w;
        #pragma unroll
        for (int j = 0; j < 8; j++)
            o[j] = o[j] > 0.f ? o[j] : __expf(o[j]) - 1.f;   // ELU
        float4* o4 = (float4*)(out + (size_t)d * DIM) + li * 2;
        o4[0] = make_float4(o[0], o[1], o[2], o[3]);
        o4[1] = make_float4(o[4], o[5], o[6], o[7]);
    }
}

// ---------------------------------------------------------------------------
extern "C" void kernel_launch(void* const* d_in, const int* in_sizes, int n_in,
                              void* d_out, int out_size, void* d_ws, size_t ws_size,
                              hipStream_t stream) {
    const float* x_food      = (const float*)d_in[0];
    const float* x_nut       = (const float*)d_in[1];
    const float* Wsrc_fn     = (const float*)d_in[2];
    const float* Wdst_fn     = (const float*)d_in[3];
    const float* att_src_fn  = (const float*)d_in[4];
    const float* att_dst_fn  = (const float*)d_in[5];
    const float* bias_fn     = (const float*)d_in[6];
    const float* Wsrc_nf     = (const float*)d_in[7];
    const float* Wdst_nf     = (const float*)d_in[8];
    const float* att_src_nf  = (const float*)d_in[9];
    const float* att_dst_nf  = (const float*)d_in[10];
    const float* bias_nf     = (const float*)d_in[11];
    const int*   ei_fn       = (const int*)d_in[12];
    const int*   ei_nf       = (const int*)d_in[13];
    float* out = (float*)d_out;

    char* ws = (char*)d_ws;
    size_t off = 0;
    auto alloc_f = [&](size_t n) { float* p = (float*)(ws + off); off += n * 4; return p; };
    auto alloc_i = [&](size_t n) { int* p = (int*)(ws + off); off += n * 4; return p; };
    auto alloc_u = [&](size_t n) { ushort* p = (ushort*)(ws + off); off += n * 2; return p; };

    float* B_food = alloc_f((size_t)NNODE * DIM);
    float* B_nut  = alloc_f((size_t)NNODE * DIM);
    ushort* HS_fn = alloc_u((size_t)NNODE * DIM);
    ushort* HS_nf = alloc_u((size_t)NNODE * DIM);
    float* AS_fn  = alloc_f(NNODE * NHEAD);
    float* AS_nf  = alloc_f(NNODE * NHEAD);
    float* AD_fn  = alloc_f(NNODE * NHEAD);
    float* AD_nf  = alloc_f(NNODE * NHEAD);
    float* wav    = alloc_f(4 * DIM * 8);
    int* ptr_fn   = alloc_i(50004);
    int* ptr_nf   = alloc_i(50004);
    ushort* srcs_fn = alloc_u(NEDGE);
    ushort* srcs_nf = alloc_u(NEDGE);
    int* bcnt     = alloc_i(512);
    unsigned* Mbuf = (unsigned*)alloc_i(16);   // [layer][rel][head]
    int* bko      = alloc_i(512);
    int* bcur     = alloc_i(512);
    // bkt buffers alias B_food/B_nut (dead until after CSR build)
    unsigned* bkt_fn = (unsigned*)B_food;
    unsigned* bkt_nf = (unsigned*)B_nut;

    // ---- CSR build: two-level counting sort (+ zero Mbuf, contiguous) ----
    hipMemsetAsync(bcnt, 0, (512 + 16) * 4, stream);
    bhist<<<2 * ECHUNK, 256, 0, stream>>>(ei_fn, ei_nf, bcnt);
    bscan<<<2, 256, 0, stream>>>(bcnt, bko, bcur, ptr_fn, ptr_nf);
    bscatter<<<2 * ECHUNK, 256, 0, stream>>>(ei_fn, ei_nf, bcur, bkt_fn, bkt_nf);
    bsort<<<2 * NBUCK, 256, 0, stream>>>(bkt_fn, bkt_nf, bko, ptr_fn, ptr_nf,
                                         srcs_fn, srcs_nf);

    prep_wav<<<4, 256, 0, stream>>>(Wsrc_fn, att_src_fn, Wdst_fn, att_dst_fn,
                                    Wsrc_nf, att_src_nf, Wdst_nf, att_dst_nf, wav);

    const int WL = DIM * DIM;
    const int TNB = 384;
    const int ANB = (NNODE + 3) / 4;
    float* wav0 = wav;
    float* wav1 = wav + DIM * 8;
    float* wav2 = wav + 2 * DIM * 8;
    float* wav3 = wav + 3 * DIM * 8;

    // ---- Layer 0 ----
    transform_kernel<<<2 * TNB, 256, 0, stream>>>(
        x_food, Wsrc_fn, wav0, HS_fn, AS_fn, AD_nf,
        x_nut,  Wsrc_nf, wav1, HS_nf, AS_nf, AD_fn, Mbuf, TNB);
    agg_kernel<<<2 * ANB, 256, 0, stream>>>(
        HS_fn, AS_fn, AD_fn, ptr_fn, srcs_fn, bias_fn, B_nut,
        HS_nf, AS_nf, AD_nf, ptr_nf, srcs_nf, bias_nf, B_food, Mbuf, ANB);

    // ---- Layer 1 -> d_out ----
    transform_kernel<<<2 * TNB, 256, 0, stream>>>(
        B_food, Wsrc_fn + WL, wav2, HS_fn, AS_fn, AD_nf,
        B_nut,  Wsrc_nf + WL, wav3, HS_nf, AS_nf, AD_fn, Mbuf + 8, TNB);
    agg_kernel<<<2 * ANB, 256, 0, stream>>>(
        HS_fn, AS_fn, AD_fn, ptr_fn, srcs_fn, bias_fn + DIM, out + (size_t)NNODE * DIM,
        HS_nf, AS_nf, AD_nf, ptr_nf, srcs_nf, bias_nf + DIM, out, Mbuf + 8, ANB);
}